// Round 7
// baseline (369.324 us; speedup 1.0000x reference)
//
#include <hip/hip_runtime.h>
#include <hip/hip_fp16.h>
#include <stdint.h>

// Problem constants (x: (2,21,256,256) f32, image: (2,3,256,256) f32, bilateral d=5)
#define BB   2
#define CC   21
#define HCP  32              // halves per lattice row (64 B = exactly 1 cache line)
#define NPT  (BB*256*256)    // 131072 points
#define DP1  6
#define NV   (NPT*DP1)       // 786432 point-vertex pairs (max unique keys)
#define TS   (1u<<20)        // hash slots (load ~52% — R14: halved for L2 hit rate)
#define TMASK (TS-1)
#define EMPTYK 0xFFFFFFFFFFFFFFFFULL
#define NBLK (NV/1024)       // 768 scan blocks (pair-count scan)
#define NBUCK 32768          // owner-pixel buckets (pixel id >> 2): dense & uniform
// 41-bit key: 5 coords x 8 bits (coord+128, each byte in [26,230]) + batch bit 40.
// bits 41..63 of the hash word: owner pixel id (build) then compact idx (place).
#define KEYMASK ((1ULL<<41)-1ULL)

// R7: do NOT swizzle blockIdx. R9: buckets must be load-uniform.
// R11/R12: fp16 64B lattice rows -> 1 line per random gather (611 -> 381 us).
// R13: insert is random-RMW-throughput-bound — more waves don't help.
// R15: LDS histogram + dead-pkeys drop: WIN. Symmetric k_nbr: WIN.
// R16: CAS-first probing REGRESSED; peek-then-CAS + 6-way batched peeks:
//      k_build 54 -> 50 us. k_build ~floor (97MB compulsory random @ ~2TB/s).
// R19 (this round): COOPERATIVE LAUNCH ABANDONED. Evidence: r5 coop launch
//      silently rejected at graph capture (output never written); r6 with
//      error-checking the container HUNG twice — consistent with the capture
//      node replaying non-cooperatively and grid.sync() deadlocking. No
//      grid-wide sync of any kind from here on.
//      Instead: (a) k_build split into 2 half-grid launches — lowers the
//      top-5 visibility threshold to ~30us so the dominant tail kernel
//      surfaces next round; (b) k_tx fused into k_build (x streaming hides
//      under random-RMW stalls; saves a launch); (c) cnt+nbry adjacent ->
//      single memset.

__device__ __forceinline__ uint64_t hmix(uint64_t x){
  x ^= x >> 33; x *= 0xff51afd7ed558ccdULL;
  x ^= x >> 33; x *= 0xc4ceb9fe1a85ec53ULL;
  x ^= x >> 33; return x;
}

__device__ __forceinline__ int hlookup(const unsigned long long* __restrict__ hs,
                                       uint64_t key){
  uint32_t h = (uint32_t)hmix(key) & TMASK;
  for (;;){
    unsigned long long e = hs[h];
    if (e == EMPTYK) return -1;
    if ((e & KEYMASK) == (unsigned long long)key) return (int)(e >> 41);
    h = (h + 1) & TMASK;
  }
}

// load first 24 halves (3x16B) of a 64B-aligned row -> 12 float2
__device__ __forceinline__ void row_load(const __half* p, float2 f[12]){
  const uint4* p4 = (const uint4*)p;
  #pragma unroll
  for (int i=0;i<3;i++){
    uint4 r = p4[i];
    const __half2* h = (const __half2*)&r;
    #pragma unroll
    for (int j=0;j<4;j++) f[i*4+j] = __half22float2(h[j]);
  }
}
// store 12 float2 -> first 24 halves of a row
__device__ __forceinline__ void row_store(__half* p, const float2 f[12]){
  uint4* p4 = (uint4*)p;
  #pragma unroll
  for (int i=0;i<3;i++){
    uint4 r;
    __half2* h = (__half2*)&r;
    #pragma unroll
    for (int j=0;j<4;j++) h[j] = __floats2half2_rn(f[i*4+j].x, f[i*4+j].y);
    p4[i] = r;
  }
}

// K1: fused transpose + per-point lattice math + hash insert (peek-then-CAS;
// 6 initial peeks as independent loads) + hslot recording. Bucket counts
// aggregate in LDS (bucket n>>2 is block-exclusive, also across half-grids).
// Launched twice with pixbase = 0 and NPT/2 (diagnostic split — see R19).
__global__ __launch_bounds__(256) void k_build(const float* __restrict__ xin,
      const float* __restrict__ img,
      unsigned long long* __restrict__ hs,
      int* __restrict__ hist,
      float* __restrict__ pbary,
      int* __restrict__ hslot,
      __half* __restrict__ xt,
      int pixbase){
  __shared__ int s_hist[64];
  int t = threadIdx.x;
  if (t < 64) s_hist[t] = 0;
  __syncthreads();
  int n = pixbase + blockIdx.x*256 + t;
  int b = n >> 16, pix = n & 65535;
  int y = pix >> 8, x = pix & 255;
  // ---- fused k_tx: issue the 21 strided x loads early; they drain under the
  // lattice math and the store lands before the hash phase's random traffic ----
  const float* xb = xin + (((size_t)b*CC) << 16) + pix;
  float v12[12*2];
  #pragma unroll
  for (int q=0;q<12;q++){
    int c0 = 2*q, c1 = 2*q+1;
    v12[2*q]   = (c0 < CC) ? xb[(size_t)c0 << 16] : 0.f;
    v12[2*q+1] = (c1 < CC) ? xb[(size_t)c1 << 16] : 0.f;
  }
  // scale[j] = sqrt(2/3)*6 / sqrt((j+1)(j+2)), as float32 (numpy f64 -> f32)
  const float sc0 = 3.4641016151377544f, sc1 = 2.0f, sc2 = 1.4142135623730951f,
              sc3 = 1.0954451150103321f, sc4 = 0.8944271909999159f;
  size_t ib = ((size_t)b*3) << 16;
  float f0 = ((float)x / 80.0f) * sc0;                      // xs / THETA_ALPHA
  float f1 = ((float)y / 80.0f) * sc1;                      // ys / THETA_ALPHA
  float f2 = (img[ib + pix]          / 13.0f) * sc2;        // R / THETA_BETA
  float f3 = (img[ib + 65536 + pix]  / 13.0f) * sc3;        // G
  float f4 = (img[ib + 131072 + pix] / 13.0f) * sc4;        // B
  // elevate: E rows [1,1,1,1,1],[-1,1,1,1,1],[0,-2,1,1,1],[0,0,-3,1,1],[0,0,0,-4,1],[0,0,0,0,-5]
  float E[6];
  {
    float s4 = f4;
    E[5] = -5.0f*f4;
    E[4] = -4.0f*f3 + s4;
    float s3 = f3 + s4;
    E[3] = -3.0f*f2 + s3;
    float s2 = f2 + s3;
    E[2] = -2.0f*f1 + s2;
    float s1 = f1 + s2;
    E[1] = -f0 + s1;
    E[0] =  f0 + s1;
  }
  float rem0[6], di[6]; int rk[6];
  float ssf = 0.f;
  #pragma unroll
  for (int i=0;i<6;i++){
    float v  = E[i] / 6.0f;
    float up = ceilf(v)*6.0f, dn = floorf(v)*6.0f;
    float r0 = (up - E[i] < E[i] - dn) ? up : dn;
    rem0[i] = r0; di[i] = E[i] - r0; ssf += r0;     // di from PRE-wrap rem0
  }
  int ssum = (int)rintf(ssf / 6.0f);                 // exact: rem0 are multiples of 6
  #pragma unroll
  for (int i=0;i<6;i++){
    int c = ssum;
    #pragma unroll
    for (int k=0;k<6;k++){
      if (k==i) continue;
      bool tt = (k>i) ? (di[i] < di[k]) : (di[i] <= di[k]);
      c += tt ? 1 : 0;
    }
    rk[i] = c;
  }
  #pragma unroll
  for (int i=0;i<6;i++){
    if      (rk[i] < 0){ rk[i] += 6; rem0[i] += 6.0f; }
    else if (rk[i] > 5){ rk[i] -= 6; rem0[i] -= 6.0f; }
  }
  // barycentric: bar[5-rk] += t; bar[6-rk] -= t  (unrolled to keep in registers)
  float bar[7] = {0,0,0,0,0,0,0};
  #pragma unroll
  for (int i=0;i<6;i++){
    float tb = (E[i] - rem0[i]) / 6.0f;              // t from POST-wrap rem0
    #pragma unroll
    for (int j=0;j<7;j++){
      bar[j] += ((5-rk[i])==j) ? tb : 0.0f;
      bar[j] -= ((6-rk[i])==j) ? tb : 0.0f;
    }
  }
  float w0 = bar[0] + 1.0f + bar[6];
  int ri[5];
  #pragma unroll
  for (int i=0;i<5;i++) ri[i] = (int)rintf(rem0[i]);
  // store the transposed x row now (loads have drained under the math above)
  row_store(xt + (size_t)n*HCP, (const float2*)v12);
  uint64_t bbit = ((uint64_t)b) << 40;
  // --- phase 1: all 6 keys + initial hash slots; issue 6 independent peeks ---
  uint64_t keyv[6]; uint32_t h0[6];
  #pragma unroll
  for (int r=0;r<6;r++){
    uint64_t key = bbit;
    #pragma unroll
    for (int i=0;i<5;i++){
      int k = ri[i] + r - ((rk[i] > 5-r) ? 6 : 0);   // |k| <= 102 -> +128 in [26,230]
      key |= ((uint64_t)(uint32_t)(k + 128) & 0xFFULL) << (8*i);
    }
    keyv[r] = key;
    h0[r] = (uint32_t)hmix(key) & TMASK;
    pbary[n*6+r] = (r==0) ? w0 : bar[r];
  }
  unsigned long long pk[6];
  #pragma unroll
  for (int r=0;r<6;r++) pk[r] = hs[h0[r]];           // 6 loads in flight
  // --- phase 2: resolve each vertex (stale peek is safe: CAS re-checks) ---
  #pragma unroll
  for (int r=0;r<6;r++){
    uint64_t key = keyv[r];
    uint64_t ins = key | ((uint64_t)(uint32_t)n << 41);   // owner embedded
    uint32_t h = h0[r];
    unsigned long long seen = pk[r];
    for (;;){
      if (seen != EMPTYK && (seen & KEYMASK) == (unsigned long long)key) break;
      if (seen == EMPTYK){
        unsigned long long prev = atomicCAS(&hs[h], EMPTYK, (unsigned long long)ins);
        if (prev == EMPTYK){
          atomicAdd(&s_hist[t >> 2], 1);   // LDS — block owns buckets (n>>2)
          break;
        }
        if ((prev & KEYMASK) == (unsigned long long)key) break;
      }
      h = (h + 1) & TMASK;
      seen = hs[h];
    }
    hslot[n*6+r] = (int)h;
  }
  __syncthreads();
  if (t < 64) hist[(pixbase >> 2) + blockIdx.x*64 + t] = s_hist[t];
}

// K2b: single-block scan of NBUCK bucket counts (32 serial buckets per thread)
__global__ __launch_bounds__(1024) void k_scan_small(const int* __restrict__ hist,
      int* __restrict__ bcur, int* __restrict__ counter){
  __shared__ int s[1024];
  int t = threadIdx.x;
  int base = t * (NBUCK/1024);
  int loc[NBUCK/1024];
  int sum = 0;
  #pragma unroll
  for (int i=0;i<NBUCK/1024;i++){ loc[i] = hist[base+i]; sum += loc[i]; }
  s[t] = sum;
  __syncthreads();
  #pragma unroll
  for (int o=1;o<1024;o<<=1){
    int add = (t>=o) ? s[t-o] : 0;
    __syncthreads();
    s[t] += add;
    __syncthreads();
  }
  int run = s[t] - sum;   // exclusive prefix for this thread's range
  #pragma unroll
  for (int i=0;i<NBUCK/1024;i++){ bcur[base+i] = run; run += loc[i]; }
  if (t == 1023) counter[0] = run;
}

// K2c: place occupied slots -> owner-bucket-ordered compact idx.
__global__ __launch_bounds__(1024) void k_place(unsigned long long* __restrict__ hs,
      int* __restrict__ bcur,
      unsigned long long* __restrict__ latkeys){
  uint32_t s = blockIdx.x*1024 + threadIdx.x;
  unsigned long long e = hs[s];
  if (e == EMPTYK) return;
  int nown = (int)(e >> 41);
  int idx = atomicAdd(&bcur[nown >> 2], 1);
  unsigned long long key = e & KEYMASK;
  hs[s] = key | ((unsigned long long)idx << 41);
  latkeys[idx] = key;
}

// K2d: precompute blur neighbor indices. Symmetry: +probe only, scatter the
// -neighbor. nbrx coalesced plane; nbry scattered 4B stores (memset to 0).
__global__ __launch_bounds__(256) void k_nbr(const unsigned long long* __restrict__ hs,
      const unsigned long long* __restrict__ latkeys, const int* __restrict__ counter,
      uint32_t* __restrict__ nbrx, uint32_t* __restrict__ nbry){
  int m = blockIdx.x*256 + threadIdx.x;
  if (m >= *counter) return;
  uint64_t key = (uint64_t)latkeys[m];
  const unsigned long long S5 = (1ULL<<32)+(1ULL<<24)+(1ULL<<16)+(1ULL<<8)+1ULL;
  #pragma unroll
  for (int j=0;j<6;j++){
    unsigned long long delta = (j<5) ? (S5 - (6ULL << (8*j))) : S5;
    int i1 = hlookup(hs, key + delta);
    nbrx[(size_t)j*NV + m] = (uint32_t)(i1+1);
    if (i1 >= 0) nbry[(size_t)j*NV + (uint32_t)i1] = (uint32_t)(m+1);
  }
}

// K3: pidx via recorded slot — ONE random 8B read, no probe chain.
__global__ __launch_bounds__(256) void k_find(const unsigned long long* __restrict__ hs,
      const int* __restrict__ hslot,
      int* __restrict__ pidx, int* __restrict__ cnt){
  int t = blockIdx.x*256 + threadIdx.x;
  if (t >= NV) return;
  int i = (int)(hs[hslot[t]] >> 41);
  pidx[t] = i;
  atomicAdd(&cnt[i], 1);
}

// Scan stage 1
__global__ __launch_bounds__(1024) void k_scan1(const int* __restrict__ cnt,
      int* __restrict__ off, int* __restrict__ bsum){
  __shared__ int s[1024];
  int t = threadIdx.x;
  int i = blockIdx.x*1024 + t;
  int v = cnt[i];
  s[t] = v;
  __syncthreads();
  #pragma unroll
  for (int o=1;o<1024;o<<=1){
    int add = (t>=o) ? s[t-o] : 0;
    __syncthreads();
    s[t] += add;
    __syncthreads();
  }
  off[i] = s[t] - v;
  if (t==1023) bsum[blockIdx.x] = s[t];
}

// Scan stage 2
__global__ __launch_bounds__(1024) void k_scan2(int* __restrict__ bsum){
  __shared__ int s[1024];
  int t = threadIdx.x;
  int v = (t < NBLK) ? bsum[t] : 0;
  s[t] = v;
  __syncthreads();
  #pragma unroll
  for (int o=1;o<1024;o<<=1){
    int add = (t>=o) ? s[t-o] : 0;
    __syncthreads();
    s[t] += add;
    __syncthreads();
  }
  if (t < NBLK) bsum[t] = s[t] - v;
}

// Scan stage 3: finalize off (exclusive prefix start). The scatter phase
// atomics on off; afterwards off[m] is the segment END.
__global__ __launch_bounds__(1024) void k_scan3(int* __restrict__ off,
      const int* __restrict__ bsum){
  int i = blockIdx.x*1024 + threadIdx.x;
  off[i] += bsum[blockIdx.x];
}

// K4a: scatter {pixel id, weight} into CSR pairlist (atomics on off)
__global__ __launch_bounds__(256) void k_scatter(const int* __restrict__ pidx,
      const float* __restrict__ pbary, int* __restrict__ off, uint2* __restrict__ plist2){
  int t = blockIdx.x*256 + threadIdx.x;
  if (t >= NV) return;
  int idx = pidx[t];
  int pos = atomicAdd(&off[idx], 1);
  plist2[pos] = make_uint2((uint32_t)(t/6), __float_as_uint(pbary[t]));
}

// K4b: gather-reduce splat — fp16 xt rows (1 line/gather), fp32 acc, fp16 store
__global__ __launch_bounds__(256) void k_splat2(const __half* __restrict__ xt,
      const int* __restrict__ off, const int* __restrict__ cnt,
      const uint2* __restrict__ plist2, const int* __restrict__ counter,
      __half* __restrict__ lat){
  int m = blockIdx.x*256 + threadIdx.x;
  if (m >= *counter) return;
  float2 acc[12];
  #pragma unroll
  for (int q=0;q<12;q++) acc[q] = make_float2(0.f,0.f);
  int e1 = off[m], k = cnt[m];             // off[m] is the segment END
  for (int e=e1-k; e<e1; ++e){
    uint2 pv = plist2[e];
    float w = __uint_as_float(pv.y);
    float2 xr[12];
    row_load(xt + (size_t)pv.x*HCP, xr);
    #pragma unroll
    for (int q=0;q<12;q++){
      acc[q].x = fmaf(w, xr[q].x, acc[q].x);
      acc[q].y = fmaf(w, xr[q].y, acc[q].y);
    }
  }
  row_store(lat + (size_t)m*HCP, acc);
}

// K5: one blur direction via precomputed neighbor planes; fp32 math, fp16 rows
__global__ __launch_bounds__(256) void k_blur(const uint32_t* __restrict__ nx,
      const uint32_t* __restrict__ ny,
      const int* __restrict__ counter, const __half* __restrict__ src,
      __half* __restrict__ dst){
  int m = blockIdx.x*256 + threadIdx.x;
  if (m >= *counter) return;
  uint32_t ex = nx[m], ey = ny[m];
  float2 a[12], u[12], v[12];
  #pragma unroll
  for (int q=0;q<12;q++){ u[q] = make_float2(0.f,0.f); v[q] = make_float2(0.f,0.f); }
  row_load(src + (size_t)m*HCP, a);
  if (ex) row_load(src + (size_t)(ex-1u)*HCP, u);
  if (ey) row_load(src + (size_t)(ey-1u)*HCP, v);
  float2 r[12];
  #pragma unroll
  for (int q=0;q<12;q++){
    r[q].x = a[q].x + 0.5f*(u[q].x + v[q].x);
    r[q].y = a[q].y + 0.5f*(u[q].y + v[q].y);
  }
  row_store(dst + (size_t)m*HCP, r);
}

// K6: slice — out[b,c,y,x] = alpha * sum_r bary[r] * lat[idx[r]][c]
__global__ __launch_bounds__(256) void k_slice(const __half* __restrict__ lat,
      const int* __restrict__ pidx, const float* __restrict__ pbary,
      float* __restrict__ out){
  int n = blockIdx.x*256 + threadIdx.x;
  if (n >= NPT) return;
  float2 acc[12];
  #pragma unroll
  for (int q=0;q<12;q++) acc[q] = make_float2(0.f,0.f);
  #pragma unroll
  for (int r=0;r<6;r++){
    int idx = pidx[n*6+r]; float w = pbary[n*6+r];
    float2 L[12];
    row_load(lat + (size_t)idx*HCP, L);
    #pragma unroll
    for (int q=0;q<12;q++){
      acc[q].x = fmaf(w, L[q].x, acc[q].x);
      acc[q].y = fmaf(w, L[q].y, acc[q].y);
    }
  }
  int b = n >> 16, pix = n & 65535;
  float* ob = out + (((size_t)b*CC) << 16) + pix;
  const float alpha = 0.9696969696969697f;  // 1/(1+2^-5) = 32/33
  #pragma unroll
  for (int c=0;c<CC;c++){
    float val = (c & 1) ? acc[c>>1].y : acc[c>>1].x;
    ob[(size_t)c << 16] = alpha * val;
  }
}

extern "C" void kernel_launch(void* const* d_in, const int* in_sizes, int n_in,
                              void* d_out, int out_size, void* d_ws, size_t ws_size,
                              hipStream_t stream){
  const float* xin = (const float*)d_in[0];   // (2,21,256,256)
  const float* img = (const float*)d_in[1];   // (2,3,256,256)
  float* out = (float*)d_out;                 // (2,21,256,256)

  // workspace carve (each region 256B-aligned); cnt+nbry ADJACENT (one memset)
  char* p = (char*)d_ws;
  auto carve = [&](size_t bytes)->char*{
    char* r = p; p += (bytes + 255) & ~(size_t)255; return r;
  };
  unsigned long long* hs      = (unsigned long long*)carve((size_t)TS*8);   //  8.4 MB
  unsigned long long* latkeys = (unsigned long long*)carve((size_t)NV*8);   //  6.3 MB
  int*                counter = (int*)               carve(256);
  uint2*              plist2  = (uint2*)             carve((size_t)NV*8);   //  6.3 MB
  int*                pidx    = (int*)               carve((size_t)NV*4);   //  3.1 MB
  float*              pbary   = (float*)             carve((size_t)NV*4);   //  3.1 MB
  int*                hslot   = (int*)               carve((size_t)NV*4);   //  3.1 MB
  int*                cnt     = (int*)               carve((size_t)NV*4);   //  3.1 MB  (zeroed ↓)
  uint32_t*           nbry    = (uint32_t*)          carve((size_t)6*NV*4); // 18.9 MB  (zeroed ↓, adjacent to cnt)
  int*                off     = (int*)               carve((size_t)NV*4);   //  3.1 MB
  int*                bsum    = (int*)               carve((size_t)NBLK*4); //  3 KB
  int*                hist    = (int*)               carve((size_t)NBUCK*4);// 128 KB (fully written by k_build)
  int*                bcur    = (int*)               carve((size_t)NBUCK*4);// 128 KB
  uint32_t*           nbrx    = (uint32_t*)          carve((size_t)6*NV*4); // 18.9 MB
  __half*             latA    = (__half*)            carve((size_t)NV*HCP*2);// 50.3 MB
  __half*             latB    = (__half*)            carve((size_t)NV*HCP*2);// 50.3 MB

  // aliases (non-overlapping liveness):
  //   xt (fp16, NPT*64B = 8.4 MB) lives in latB — written by k_build, read
  //   only by k_splat2; blur j=0 overwrites latB strictly after splat.
  __half* xt = latB;

  (void)hipMemsetAsync(hs, 0xFF, (size_t)TS*8, stream);
  (void)hipMemsetAsync(cnt, 0, (size_t)(NV*4 + (size_t)6*NV*4), stream); // cnt+nbry

  // build split in two half-grids (R19 diagnostic: halves ~27-32us lower the
  // rocprof top-5 threshold so the dominant tail kernel becomes visible)
  k_build<<<NPT/512, 256, 0, stream>>>(xin, img, hs, hist, pbary, hslot, xt, 0);
  k_build<<<NPT/512, 256, 0, stream>>>(xin, img, hs, hist, pbary, hslot, xt, NPT/2);
  k_scan_small<<<1,      1024, 0, stream>>>(hist, bcur, counter);
  k_place     <<<TS/1024,1024, 0, stream>>>(hs, bcur, latkeys);
  k_nbr       <<<NV/256,  256, 0, stream>>>(hs, latkeys, counter, nbrx, nbry);
  k_find      <<<NV/256,  256, 0, stream>>>(hs, hslot, pidx, cnt);
  k_scan1     <<<NBLK,   1024, 0, stream>>>(cnt, off, bsum);
  k_scan2     <<<1,      1024, 0, stream>>>(bsum);
  k_scan3     <<<NBLK,   1024, 0, stream>>>(off, bsum);
  k_scatter   <<<NV/256,  256, 0, stream>>>(pidx, pbary, off, plist2);
  k_splat2    <<<NV/256,  256, 0, stream>>>(xt, off, cnt, plist2, counter, latA);

  // 6 blur passes, ping-pong latA <-> latB, using precomputed neighbor planes
  __half* src = latA; __half* dst = latB;
  for (int j=0;j<6;j++){
    k_blur<<<NV/256, 256, 0, stream>>>(nbrx + (size_t)j*NV, nbry + (size_t)j*NV,
                                       counter, src, dst);
    __half* tmp = src; src = dst; dst = tmp;
  }
  // after 6 swaps src == latA (final)
  k_slice<<<NPT/256, 256, 0, stream>>>(src, pidx, pbary, out);
}

// Round 8
// 348.180 us; speedup vs baseline: 1.0607x; 1.0607x over previous
//
#include <hip/hip_runtime.h>
#include <hip/hip_fp16.h>
#include <stdint.h>

// Problem constants (x: (2,21,256,256) f32, image: (2,3,256,256) f32, bilateral d=5)
#define BB   2
#define CC   21
#define HCP  32              // halves per lattice row (64 B = exactly 1 cache line)
#define NPT  (BB*256*256)    // 131072 points
#define DP1  6
#define NV   (NPT*DP1)       // 786432 point-vertex pairs (max unique keys)
#define TS   (1u<<20)        // hash slots (load ~52% — R14: halved for L2 hit rate)
#define TMASK (TS-1)
#define EMPTYK 0xFFFFFFFFFFFFFFFFULL
#define NBLK (NV/1024)       // 768 scan blocks (pair-count scan)
#define NBUCK 32768          // owner-pixel buckets (pixel id >> 2): dense & uniform
// 41-bit key: 5 coords x 8 bits (coord+128, each byte in [26,230]) + batch bit 40.
// bits 41..63 of the hash word: owner pixel id (build) then compact idx (place).
#define KEYMASK ((1ULL<<41)-1ULL)

// R7: do NOT swizzle blockIdx. R9: buckets must be load-uniform.
// R11/R12: fp16 64B lattice rows -> 1 line per random gather (611 -> 381 us).
// R13: insert is random-RMW-throughput-bound — more waves don't help.
// R15: LDS histogram + dead-pkeys drop: WIN. Symmetric k_nbr: WIN.
// R16: CAS-first probing REGRESSED; peek-then-CAS + 6-way batched peeks:
//      k_build 54 -> 50 us. k_build ~floor (97MB compulsory random @ ~2TB/s).
// R19: cooperative launch ABANDONED (r5 silent reject, r6 hang under graph
//      capture). Build split 2x half-grid (diagnostic) + k_tx fused into build.
// R20 (this round): diagnostic surfaced k_scatter = 45.7us, WRITE 38.5MB vs
//      6.3MB useful — 786K atomicAdd(&off) RMWs at the coherence point. But
//      k_find's atomicAdd(&cnt) ALREADY computes each pair's segment rank and
//      discards it. Record it (reusing hslot, dead after k_find) -> k_scatter
//      becomes atomic-free: pos = off[idx] + rank. off never mutated; splat
//      reads [off[m], off[m]+cnt[m]). One random-atomic histogram, not two.

__device__ __forceinline__ uint64_t hmix(uint64_t x){
  x ^= x >> 33; x *= 0xff51afd7ed558ccdULL;
  x ^= x >> 33; x *= 0xc4ceb9fe1a85ec53ULL;
  x ^= x >> 33; return x;
}

__device__ __forceinline__ int hlookup(const unsigned long long* __restrict__ hs,
                                       uint64_t key){
  uint32_t h = (uint32_t)hmix(key) & TMASK;
  for (;;){
    unsigned long long e = hs[h];
    if (e == EMPTYK) return -1;
    if ((e & KEYMASK) == (unsigned long long)key) return (int)(e >> 41);
    h = (h + 1) & TMASK;
  }
}

// load first 24 halves (3x16B) of a 64B-aligned row -> 12 float2
__device__ __forceinline__ void row_load(const __half* p, float2 f[12]){
  const uint4* p4 = (const uint4*)p;
  #pragma unroll
  for (int i=0;i<3;i++){
    uint4 r = p4[i];
    const __half2* h = (const __half2*)&r;
    #pragma unroll
    for (int j=0;j<4;j++) f[i*4+j] = __half22float2(h[j]);
  }
}
// store 12 float2 -> first 24 halves of a row
__device__ __forceinline__ void row_store(__half* p, const float2 f[12]){
  uint4* p4 = (uint4*)p;
  #pragma unroll
  for (int i=0;i<3;i++){
    uint4 r;
    __half2* h = (__half2*)&r;
    #pragma unroll
    for (int j=0;j<4;j++) h[j] = __floats2half2_rn(f[i*4+j].x, f[i*4+j].y);
    p4[i] = r;
  }
}

// K1: fused transpose + per-point lattice math + hash insert (peek-then-CAS;
// 6 initial peeks as independent loads) + hslot recording. Bucket counts
// aggregate in LDS (bucket n>>2 is block-exclusive, also across half-grids).
// Launched twice with pixbase = 0 and NPT/2.
__global__ __launch_bounds__(256) void k_build(const float* __restrict__ xin,
      const float* __restrict__ img,
      unsigned long long* __restrict__ hs,
      int* __restrict__ hist,
      float* __restrict__ pbary,
      int* __restrict__ hslot,
      __half* __restrict__ xt,
      int pixbase){
  __shared__ int s_hist[64];
  int t = threadIdx.x;
  if (t < 64) s_hist[t] = 0;
  __syncthreads();
  int n = pixbase + blockIdx.x*256 + t;
  int b = n >> 16, pix = n & 65535;
  int y = pix >> 8, x = pix & 255;
  // ---- fused k_tx: issue the 21 strided x loads early; they drain under the
  // lattice math and the store lands before the hash phase's random traffic ----
  const float* xb = xin + (((size_t)b*CC) << 16) + pix;
  float v12[12*2];
  #pragma unroll
  for (int q=0;q<12;q++){
    int c0 = 2*q, c1 = 2*q+1;
    v12[2*q]   = (c0 < CC) ? xb[(size_t)c0 << 16] : 0.f;
    v12[2*q+1] = (c1 < CC) ? xb[(size_t)c1 << 16] : 0.f;
  }
  // scale[j] = sqrt(2/3)*6 / sqrt((j+1)(j+2)), as float32 (numpy f64 -> f32)
  const float sc0 = 3.4641016151377544f, sc1 = 2.0f, sc2 = 1.4142135623730951f,
              sc3 = 1.0954451150103321f, sc4 = 0.8944271909999159f;
  size_t ib = ((size_t)b*3) << 16;
  float f0 = ((float)x / 80.0f) * sc0;                      // xs / THETA_ALPHA
  float f1 = ((float)y / 80.0f) * sc1;                      // ys / THETA_ALPHA
  float f2 = (img[ib + pix]          / 13.0f) * sc2;        // R / THETA_BETA
  float f3 = (img[ib + 65536 + pix]  / 13.0f) * sc3;        // G
  float f4 = (img[ib + 131072 + pix] / 13.0f) * sc4;        // B
  // elevate: E rows [1,1,1,1,1],[-1,1,1,1,1],[0,-2,1,1,1],[0,0,-3,1,1],[0,0,0,-4,1],[0,0,0,0,-5]
  float E[6];
  {
    float s4 = f4;
    E[5] = -5.0f*f4;
    E[4] = -4.0f*f3 + s4;
    float s3 = f3 + s4;
    E[3] = -3.0f*f2 + s3;
    float s2 = f2 + s3;
    E[2] = -2.0f*f1 + s2;
    float s1 = f1 + s2;
    E[1] = -f0 + s1;
    E[0] =  f0 + s1;
  }
  float rem0[6], di[6]; int rk[6];
  float ssf = 0.f;
  #pragma unroll
  for (int i=0;i<6;i++){
    float v  = E[i] / 6.0f;
    float up = ceilf(v)*6.0f, dn = floorf(v)*6.0f;
    float r0 = (up - E[i] < E[i] - dn) ? up : dn;
    rem0[i] = r0; di[i] = E[i] - r0; ssf += r0;     // di from PRE-wrap rem0
  }
  int ssum = (int)rintf(ssf / 6.0f);                 // exact: rem0 are multiples of 6
  #pragma unroll
  for (int i=0;i<6;i++){
    int c = ssum;
    #pragma unroll
    for (int k=0;k<6;k++){
      if (k==i) continue;
      bool tt = (k>i) ? (di[i] < di[k]) : (di[i] <= di[k]);
      c += tt ? 1 : 0;
    }
    rk[i] = c;
  }
  #pragma unroll
  for (int i=0;i<6;i++){
    if      (rk[i] < 0){ rk[i] += 6; rem0[i] += 6.0f; }
    else if (rk[i] > 5){ rk[i] -= 6; rem0[i] -= 6.0f; }
  }
  // barycentric: bar[5-rk] += t; bar[6-rk] -= t  (unrolled to keep in registers)
  float bar[7] = {0,0,0,0,0,0,0};
  #pragma unroll
  for (int i=0;i<6;i++){
    float tb = (E[i] - rem0[i]) / 6.0f;              // t from POST-wrap rem0
    #pragma unroll
    for (int j=0;j<7;j++){
      bar[j] += ((5-rk[i])==j) ? tb : 0.0f;
      bar[j] -= ((6-rk[i])==j) ? tb : 0.0f;
    }
  }
  float w0 = bar[0] + 1.0f + bar[6];
  int ri[5];
  #pragma unroll
  for (int i=0;i<5;i++) ri[i] = (int)rintf(rem0[i]);
  // store the transposed x row now (loads have drained under the math above)
  row_store(xt + (size_t)n*HCP, (const float2*)v12);
  uint64_t bbit = ((uint64_t)b) << 40;
  // --- phase 1: all 6 keys + initial hash slots; issue 6 independent peeks ---
  uint64_t keyv[6]; uint32_t h0[6];
  #pragma unroll
  for (int r=0;r<6;r++){
    uint64_t key = bbit;
    #pragma unroll
    for (int i=0;i<5;i++){
      int k = ri[i] + r - ((rk[i] > 5-r) ? 6 : 0);   // |k| <= 102 -> +128 in [26,230]
      key |= ((uint64_t)(uint32_t)(k + 128) & 0xFFULL) << (8*i);
    }
    keyv[r] = key;
    h0[r] = (uint32_t)hmix(key) & TMASK;
    pbary[n*6+r] = (r==0) ? w0 : bar[r];
  }
  unsigned long long pk[6];
  #pragma unroll
  for (int r=0;r<6;r++) pk[r] = hs[h0[r]];           // 6 loads in flight
  // --- phase 2: resolve each vertex (stale peek is safe: CAS re-checks) ---
  #pragma unroll
  for (int r=0;r<6;r++){
    uint64_t key = keyv[r];
    uint64_t ins = key | ((uint64_t)(uint32_t)n << 41);   // owner embedded
    uint32_t h = h0[r];
    unsigned long long seen = pk[r];
    for (;;){
      if (seen != EMPTYK && (seen & KEYMASK) == (unsigned long long)key) break;
      if (seen == EMPTYK){
        unsigned long long prev = atomicCAS(&hs[h], EMPTYK, (unsigned long long)ins);
        if (prev == EMPTYK){
          atomicAdd(&s_hist[t >> 2], 1);   // LDS — block owns buckets (n>>2)
          break;
        }
        if ((prev & KEYMASK) == (unsigned long long)key) break;
      }
      h = (h + 1) & TMASK;
      seen = hs[h];
    }
    hslot[n*6+r] = (int)h;
  }
  __syncthreads();
  if (t < 64) hist[(pixbase >> 2) + blockIdx.x*64 + t] = s_hist[t];
}

// K2b: single-block scan of NBUCK bucket counts (32 serial buckets per thread)
__global__ __launch_bounds__(1024) void k_scan_small(const int* __restrict__ hist,
      int* __restrict__ bcur, int* __restrict__ counter){
  __shared__ int s[1024];
  int t = threadIdx.x;
  int base = t * (NBUCK/1024);
  int loc[NBUCK/1024];
  int sum = 0;
  #pragma unroll
  for (int i=0;i<NBUCK/1024;i++){ loc[i] = hist[base+i]; sum += loc[i]; }
  s[t] = sum;
  __syncthreads();
  #pragma unroll
  for (int o=1;o<1024;o<<=1){
    int add = (t>=o) ? s[t-o] : 0;
    __syncthreads();
    s[t] += add;
    __syncthreads();
  }
  int run = s[t] - sum;   // exclusive prefix for this thread's range
  #pragma unroll
  for (int i=0;i<NBUCK/1024;i++){ bcur[base+i] = run; run += loc[i]; }
  if (t == 1023) counter[0] = run;
}

// K2c: place occupied slots -> owner-bucket-ordered compact idx.
__global__ __launch_bounds__(1024) void k_place(unsigned long long* __restrict__ hs,
      int* __restrict__ bcur,
      unsigned long long* __restrict__ latkeys){
  uint32_t s = blockIdx.x*1024 + threadIdx.x;
  unsigned long long e = hs[s];
  if (e == EMPTYK) return;
  int nown = (int)(e >> 41);
  int idx = atomicAdd(&bcur[nown >> 2], 1);
  unsigned long long key = e & KEYMASK;
  hs[s] = key | ((unsigned long long)idx << 41);
  latkeys[idx] = key;
}

// K2d: precompute blur neighbor indices. Symmetry: +probe only, scatter the
// -neighbor. nbrx coalesced plane; nbry scattered 4B stores (memset to 0).
__global__ __launch_bounds__(256) void k_nbr(const unsigned long long* __restrict__ hs,
      const unsigned long long* __restrict__ latkeys, const int* __restrict__ counter,
      uint32_t* __restrict__ nbrx, uint32_t* __restrict__ nbry){
  int m = blockIdx.x*256 + threadIdx.x;
  if (m >= *counter) return;
  uint64_t key = (uint64_t)latkeys[m];
  const unsigned long long S5 = (1ULL<<32)+(1ULL<<24)+(1ULL<<16)+(1ULL<<8)+1ULL;
  #pragma unroll
  for (int j=0;j<6;j++){
    unsigned long long delta = (j<5) ? (S5 - (6ULL << (8*j))) : S5;
    int i1 = hlookup(hs, key + delta);
    nbrx[(size_t)j*NV + m] = (uint32_t)(i1+1);
    if (i1 >= 0) nbry[(size_t)j*NV + (uint32_t)i1] = (uint32_t)(m+1);
  }
}

// K3: pidx via recorded slot (ONE random 8B read) + segment-rank histogram.
// The atomicAdd return IS the pair's rank within its vertex segment — record
// it in hslot (read-then-overwrite, hslot dead afterwards). R20.
__global__ __launch_bounds__(256) void k_find(const unsigned long long* __restrict__ hs,
      int* __restrict__ hslot,
      int* __restrict__ pidx, int* __restrict__ cnt){
  int t = blockIdx.x*256 + threadIdx.x;
  if (t >= NV) return;
  int i = (int)(hs[hslot[t]] >> 41);
  pidx[t] = i;
  hslot[t] = atomicAdd(&cnt[i], 1);     // rank within segment
}

// Scan stage 1
__global__ __launch_bounds__(1024) void k_scan1(const int* __restrict__ cnt,
      int* __restrict__ off, int* __restrict__ bsum){
  __shared__ int s[1024];
  int t = threadIdx.x;
  int i = blockIdx.x*1024 + t;
  int v = cnt[i];
  s[t] = v;
  __syncthreads();
  #pragma unroll
  for (int o=1;o<1024;o<<=1){
    int add = (t>=o) ? s[t-o] : 0;
    __syncthreads();
    s[t] += add;
    __syncthreads();
  }
  off[i] = s[t] - v;
  if (t==1023) bsum[blockIdx.x] = s[t];
}

// Scan stage 2
__global__ __launch_bounds__(1024) void k_scan2(int* __restrict__ bsum){
  __shared__ int s[1024];
  int t = threadIdx.x;
  int v = (t < NBLK) ? bsum[t] : 0;
  s[t] = v;
  __syncthreads();
  #pragma unroll
  for (int o=1;o<1024;o<<=1){
    int add = (t>=o) ? s[t-o] : 0;
    __syncthreads();
    s[t] += add;
    __syncthreads();
  }
  if (t < NBLK) bsum[t] = s[t] - v;
}

// Scan stage 3: finalize off (exclusive segment START; never mutated again)
__global__ __launch_bounds__(1024) void k_scan3(int* __restrict__ off,
      const int* __restrict__ bsum){
  int i = blockIdx.x*1024 + threadIdx.x;
  off[i] += bsum[blockIdx.x];
}

// K4a: ATOMIC-FREE scatter — pos = off[vertex] + rank (recorded by k_find).
// 3 coalesced reads + 1 L2-cached random read (off, 2.1MB) + scattered 8B store.
__global__ __launch_bounds__(256) void k_scatter(const int* __restrict__ pidx,
      const int* __restrict__ prank,
      const float* __restrict__ pbary, const int* __restrict__ off,
      uint2* __restrict__ plist2){
  int t = blockIdx.x*256 + threadIdx.x;
  if (t >= NV) return;
  int pos = off[pidx[t]] + prank[t];
  plist2[pos] = make_uint2((uint32_t)(t/6), __float_as_uint(pbary[t]));
}

// K4b: gather-reduce splat — fp16 xt rows (1 line/gather), fp32 acc, fp16 store
__global__ __launch_bounds__(256) void k_splat2(const __half* __restrict__ xt,
      const int* __restrict__ off, const int* __restrict__ cnt,
      const uint2* __restrict__ plist2, const int* __restrict__ counter,
      __half* __restrict__ lat){
  int m = blockIdx.x*256 + threadIdx.x;
  if (m >= *counter) return;
  float2 acc[12];
  #pragma unroll
  for (int q=0;q<12;q++) acc[q] = make_float2(0.f,0.f);
  int e0 = off[m], k = cnt[m];             // off[m] is the segment START
  for (int e=e0; e<e0+k; ++e){
    uint2 pv = plist2[e];
    float w = __uint_as_float(pv.y);
    float2 xr[12];
    row_load(xt + (size_t)pv.x*HCP, xr);
    #pragma unroll
    for (int q=0;q<12;q++){
      acc[q].x = fmaf(w, xr[q].x, acc[q].x);
      acc[q].y = fmaf(w, xr[q].y, acc[q].y);
    }
  }
  row_store(lat + (size_t)m*HCP, acc);
}

// K5: one blur direction via precomputed neighbor planes; fp32 math, fp16 rows
__global__ __launch_bounds__(256) void k_blur(const uint32_t* __restrict__ nx,
      const uint32_t* __restrict__ ny,
      const int* __restrict__ counter, const __half* __restrict__ src,
      __half* __restrict__ dst){
  int m = blockIdx.x*256 + threadIdx.x;
  if (m >= *counter) return;
  uint32_t ex = nx[m], ey = ny[m];
  float2 a[12], u[12], v[12];
  #pragma unroll
  for (int q=0;q<12;q++){ u[q] = make_float2(0.f,0.f); v[q] = make_float2(0.f,0.f); }
  row_load(src + (size_t)m*HCP, a);
  if (ex) row_load(src + (size_t)(ex-1u)*HCP, u);
  if (ey) row_load(src + (size_t)(ey-1u)*HCP, v);
  float2 r[12];
  #pragma unroll
  for (int q=0;q<12;q++){
    r[q].x = a[q].x + 0.5f*(u[q].x + v[q].x);
    r[q].y = a[q].y + 0.5f*(u[q].y + v[q].y);
  }
  row_store(dst + (size_t)m*HCP, r);
}

// K6: slice — out[b,c,y,x] = alpha * sum_r bary[r] * lat[idx[r]][c]
__global__ __launch_bounds__(256) void k_slice(const __half* __restrict__ lat,
      const int* __restrict__ pidx, const float* __restrict__ pbary,
      float* __restrict__ out){
  int n = blockIdx.x*256 + threadIdx.x;
  if (n >= NPT) return;
  float2 acc[12];
  #pragma unroll
  for (int q=0;q<12;q++) acc[q] = make_float2(0.f,0.f);
  #pragma unroll
  for (int r=0;r<6;r++){
    int idx = pidx[n*6+r]; float w = pbary[n*6+r];
    float2 L[12];
    row_load(lat + (size_t)idx*HCP, L);
    #pragma unroll
    for (int q=0;q<12;q++){
      acc[q].x = fmaf(w, L[q].x, acc[q].x);
      acc[q].y = fmaf(w, L[q].y, acc[q].y);
    }
  }
  int b = n >> 16, pix = n & 65535;
  float* ob = out + (((size_t)b*CC) << 16) + pix;
  const float alpha = 0.9696969696969697f;  // 1/(1+2^-5) = 32/33
  #pragma unroll
  for (int c=0;c<CC;c++){
    float val = (c & 1) ? acc[c>>1].y : acc[c>>1].x;
    ob[(size_t)c << 16] = alpha * val;
  }
}

extern "C" void kernel_launch(void* const* d_in, const int* in_sizes, int n_in,
                              void* d_out, int out_size, void* d_ws, size_t ws_size,
                              hipStream_t stream){
  const float* xin = (const float*)d_in[0];   // (2,21,256,256)
  const float* img = (const float*)d_in[1];   // (2,3,256,256)
  float* out = (float*)d_out;                 // (2,21,256,256)

  // workspace carve (each region 256B-aligned); cnt+nbry ADJACENT (one memset)
  char* p = (char*)d_ws;
  auto carve = [&](size_t bytes)->char*{
    char* r = p; p += (bytes + 255) & ~(size_t)255; return r;
  };
  unsigned long long* hs      = (unsigned long long*)carve((size_t)TS*8);   //  8.4 MB
  unsigned long long* latkeys = (unsigned long long*)carve((size_t)NV*8);   //  6.3 MB
  int*                counter = (int*)               carve(256);
  uint2*              plist2  = (uint2*)             carve((size_t)NV*8);   //  6.3 MB
  int*                pidx    = (int*)               carve((size_t)NV*4);   //  3.1 MB
  float*              pbary   = (float*)             carve((size_t)NV*4);   //  3.1 MB
  int*                hslot   = (int*)               carve((size_t)NV*4);   //  3.1 MB (-> prank after k_find)
  int*                cnt     = (int*)               carve((size_t)NV*4);   //  3.1 MB  (zeroed ↓)
  uint32_t*           nbry    = (uint32_t*)          carve((size_t)6*NV*4); // 18.9 MB  (zeroed ↓, adjacent to cnt)
  int*                off     = (int*)               carve((size_t)NV*4);   //  3.1 MB
  int*                bsum    = (int*)               carve((size_t)NBLK*4); //  3 KB
  int*                hist    = (int*)               carve((size_t)NBUCK*4);// 128 KB (fully written by k_build)
  int*                bcur    = (int*)               carve((size_t)NBUCK*4);// 128 KB
  uint32_t*           nbrx    = (uint32_t*)          carve((size_t)6*NV*4); // 18.9 MB
  __half*             latA    = (__half*)            carve((size_t)NV*HCP*2);// 50.3 MB
  __half*             latB    = (__half*)            carve((size_t)NV*HCP*2);// 50.3 MB

  // aliases (non-overlapping liveness):
  //   xt (fp16, NPT*64B = 8.4 MB) lives in latB — written by k_build, read
  //   only by k_splat2; blur j=0 overwrites latB strictly after splat.
  __half* xt = latB;

  (void)hipMemsetAsync(hs, 0xFF, (size_t)TS*8, stream);
  (void)hipMemsetAsync(cnt, 0, (size_t)(NV*4 + (size_t)6*NV*4), stream); // cnt+nbry

  // build split in two half-grids (keeps top-5 visibility threshold low)
  k_build<<<NPT/512, 256, 0, stream>>>(xin, img, hs, hist, pbary, hslot, xt, 0);
  k_build<<<NPT/512, 256, 0, stream>>>(xin, img, hs, hist, pbary, hslot, xt, NPT/2);
  k_scan_small<<<1,      1024, 0, stream>>>(hist, bcur, counter);
  k_place     <<<TS/1024,1024, 0, stream>>>(hs, bcur, latkeys);
  k_nbr       <<<NV/256,  256, 0, stream>>>(hs, latkeys, counter, nbrx, nbry);
  k_find      <<<NV/256,  256, 0, stream>>>(hs, hslot, pidx, cnt);
  k_scan1     <<<NBLK,   1024, 0, stream>>>(cnt, off, bsum);
  k_scan2     <<<1,      1024, 0, stream>>>(bsum);
  k_scan3     <<<NBLK,   1024, 0, stream>>>(off, bsum);
  k_scatter   <<<NV/256,  256, 0, stream>>>(pidx, hslot, pbary, off, plist2);
  k_splat2    <<<NV/256,  256, 0, stream>>>(xt, off, cnt, plist2, counter, latA);

  // 6 blur passes, ping-pong latA <-> latB, using precomputed neighbor planes
  __half* src = latA; __half* dst = latB;
  for (int j=0;j<6;j++){
    k_blur<<<NV/256, 256, 0, stream>>>(nbrx + (size_t)j*NV, nbry + (size_t)j*NV,
                                       counter, src, dst);
    __half* tmp = src; src = dst; dst = tmp;
  }
  // after 6 swaps src == latA (final)
  k_slice<<<NPT/256, 256, 0, stream>>>(src, pidx, pbary, out);
}

// Round 9
// 341.869 us; speedup vs baseline: 1.0803x; 1.0185x over previous
//
#include <hip/hip_runtime.h>
#include <hip/hip_fp16.h>
#include <stdint.h>

// Problem constants (x: (2,21,256,256) f32, image: (2,3,256,256) f32, bilateral d=5)
#define BB   2
#define CC   21
#define HCP  32              // halves per lattice row (64 B = exactly 1 cache line)
#define NPT  (BB*256*256)    // 131072 points
#define DP1  6
#define NV   (NPT*DP1)       // 786432 point-vertex pairs (max unique keys)
#define TS   (1u<<20)        // hash slots (load ~52% — R14: halved for L2 hit rate)
#define TMASK (TS-1)
#define EMPTYK 0xFFFFFFFFFFFFFFFFULL
#define NBLK (NV/1024)       // 768 scan blocks (pair-count scan)
#define NBUCK 32768          // owner-pixel buckets (pixel id >> 2): dense & uniform
// 41-bit key: 5 coords x 8 bits (coord+128, each byte in [26,230]) + batch bit 40.
// bits 41..63 of the hash word: owner pixel id (build) then compact idx (place).
#define KEYMASK ((1ULL<<41)-1ULL)

// R7: do NOT swizzle blockIdx. R9: buckets must be load-uniform.
// R11/R12: fp16 64B lattice rows -> 1 line per random gather (611 -> 381 us).
// R13 (REVISED R21): insert is random-RMW-throughput-bound at >=8 waves/CU;
//      BELOW that, throughput scales with waves (half-grid = 4 waves/CU ran at
//      1.1 TB/s vs 1.94 TB/s full-grid — r8 counters). Never shrink the grid.
// R15: LDS histogram + dead-pkeys drop: WIN. Symmetric k_nbr: WIN.
// R16: CAS-first probing REGRESSED; peek-then-CAS + 6-way batched peeks:
//      k_build 54 -> 50 us. k_build ~floor (97MB compulsory random @ ~2TB/s).
// R19: cooperative launch ABANDONED (r5 silent reject, r6 hang under capture).
// R20: k_find records its atomicAdd return (= segment rank) into hslot ->
//      k_scatter atomic-free (pos = off[idx]+rank): 45.7us -> <~12us. WIN.
// R21 (this round): re-merge k_build into ONE full-grid launch (the r7 split
//      was a diagnostic; it found k_scatter, job done). Keep k_tx fused.

__device__ __forceinline__ uint64_t hmix(uint64_t x){
  x ^= x >> 33; x *= 0xff51afd7ed558ccdULL;
  x ^= x >> 33; x *= 0xc4ceb9fe1a85ec53ULL;
  x ^= x >> 33; return x;
}

__device__ __forceinline__ int hlookup(const unsigned long long* __restrict__ hs,
                                       uint64_t key){
  uint32_t h = (uint32_t)hmix(key) & TMASK;
  for (;;){
    unsigned long long e = hs[h];
    if (e == EMPTYK) return -1;
    if ((e & KEYMASK) == (unsigned long long)key) return (int)(e >> 41);
    h = (h + 1) & TMASK;
  }
}

// load first 24 halves (3x16B) of a 64B-aligned row -> 12 float2
__device__ __forceinline__ void row_load(const __half* p, float2 f[12]){
  const uint4* p4 = (const uint4*)p;
  #pragma unroll
  for (int i=0;i<3;i++){
    uint4 r = p4[i];
    const __half2* h = (const __half2*)&r;
    #pragma unroll
    for (int j=0;j<4;j++) f[i*4+j] = __half22float2(h[j]);
  }
}
// store 12 float2 -> first 24 halves of a row
__device__ __forceinline__ void row_store(__half* p, const float2 f[12]){
  uint4* p4 = (uint4*)p;
  #pragma unroll
  for (int i=0;i<3;i++){
    uint4 r;
    __half2* h = (__half2*)&r;
    #pragma unroll
    for (int j=0;j<4;j++) h[j] = __floats2half2_rn(f[i*4+j].x, f[i*4+j].y);
    p4[i] = r;
  }
}

// K1: fused transpose + per-point lattice math + hash insert (peek-then-CAS;
// 6 initial peeks as independent loads) + hslot recording. Bucket counts
// aggregate in LDS (bucket n>>2 is block-exclusive). Single full-grid launch
// (R21: 8 waves/CU needed to saturate random-RMW throughput).
__global__ __launch_bounds__(256) void k_build(const float* __restrict__ xin,
      const float* __restrict__ img,
      unsigned long long* __restrict__ hs,
      int* __restrict__ hist,
      float* __restrict__ pbary,
      int* __restrict__ hslot,
      __half* __restrict__ xt){
  __shared__ int s_hist[64];
  int t = threadIdx.x;
  if (t < 64) s_hist[t] = 0;
  __syncthreads();
  int n = blockIdx.x*256 + t;          // grid is exact: NPT/256 blocks
  int b = n >> 16, pix = n & 65535;
  int y = pix >> 8, x = pix & 255;
  // ---- fused k_tx: issue the 21 strided x loads early; they drain under the
  // lattice math and the store lands before the hash phase's random traffic ----
  const float* xb = xin + (((size_t)b*CC) << 16) + pix;
  float v12[12*2];
  #pragma unroll
  for (int q=0;q<12;q++){
    int c0 = 2*q, c1 = 2*q+1;
    v12[2*q]   = (c0 < CC) ? xb[(size_t)c0 << 16] : 0.f;
    v12[2*q+1] = (c1 < CC) ? xb[(size_t)c1 << 16] : 0.f;
  }
  // scale[j] = sqrt(2/3)*6 / sqrt((j+1)(j+2)), as float32 (numpy f64 -> f32)
  const float sc0 = 3.4641016151377544f, sc1 = 2.0f, sc2 = 1.4142135623730951f,
              sc3 = 1.0954451150103321f, sc4 = 0.8944271909999159f;
  size_t ib = ((size_t)b*3) << 16;
  float f0 = ((float)x / 80.0f) * sc0;                      // xs / THETA_ALPHA
  float f1 = ((float)y / 80.0f) * sc1;                      // ys / THETA_ALPHA
  float f2 = (img[ib + pix]          / 13.0f) * sc2;        // R / THETA_BETA
  float f3 = (img[ib + 65536 + pix]  / 13.0f) * sc3;        // G
  float f4 = (img[ib + 131072 + pix] / 13.0f) * sc4;        // B
  // elevate: E rows [1,1,1,1,1],[-1,1,1,1,1],[0,-2,1,1,1],[0,0,-3,1,1],[0,0,0,-4,1],[0,0,0,0,-5]
  float E[6];
  {
    float s4 = f4;
    E[5] = -5.0f*f4;
    E[4] = -4.0f*f3 + s4;
    float s3 = f3 + s4;
    E[3] = -3.0f*f2 + s3;
    float s2 = f2 + s3;
    E[2] = -2.0f*f1 + s2;
    float s1 = f1 + s2;
    E[1] = -f0 + s1;
    E[0] =  f0 + s1;
  }
  float rem0[6], di[6]; int rk[6];
  float ssf = 0.f;
  #pragma unroll
  for (int i=0;i<6;i++){
    float v  = E[i] / 6.0f;
    float up = ceilf(v)*6.0f, dn = floorf(v)*6.0f;
    float r0 = (up - E[i] < E[i] - dn) ? up : dn;
    rem0[i] = r0; di[i] = E[i] - r0; ssf += r0;     // di from PRE-wrap rem0
  }
  int ssum = (int)rintf(ssf / 6.0f);                 // exact: rem0 are multiples of 6
  #pragma unroll
  for (int i=0;i<6;i++){
    int c = ssum;
    #pragma unroll
    for (int k=0;k<6;k++){
      if (k==i) continue;
      bool tt = (k>i) ? (di[i] < di[k]) : (di[i] <= di[k]);
      c += tt ? 1 : 0;
    }
    rk[i] = c;
  }
  #pragma unroll
  for (int i=0;i<6;i++){
    if      (rk[i] < 0){ rk[i] += 6; rem0[i] += 6.0f; }
    else if (rk[i] > 5){ rk[i] -= 6; rem0[i] -= 6.0f; }
  }
  // barycentric: bar[5-rk] += t; bar[6-rk] -= t  (unrolled to keep in registers)
  float bar[7] = {0,0,0,0,0,0,0};
  #pragma unroll
  for (int i=0;i<6;i++){
    float tb = (E[i] - rem0[i]) / 6.0f;              // t from POST-wrap rem0
    #pragma unroll
    for (int j=0;j<7;j++){
      bar[j] += ((5-rk[i])==j) ? tb : 0.0f;
      bar[j] -= ((6-rk[i])==j) ? tb : 0.0f;
    }
  }
  float w0 = bar[0] + 1.0f + bar[6];
  int ri[5];
  #pragma unroll
  for (int i=0;i<5;i++) ri[i] = (int)rintf(rem0[i]);
  // store the transposed x row now (loads have drained under the math above)
  row_store(xt + (size_t)n*HCP, (const float2*)v12);
  uint64_t bbit = ((uint64_t)b) << 40;
  // --- phase 1: all 6 keys + initial hash slots; issue 6 independent peeks ---
  uint64_t keyv[6]; uint32_t h0[6];
  #pragma unroll
  for (int r=0;r<6;r++){
    uint64_t key = bbit;
    #pragma unroll
    for (int i=0;i<5;i++){
      int k = ri[i] + r - ((rk[i] > 5-r) ? 6 : 0);   // |k| <= 102 -> +128 in [26,230]
      key |= ((uint64_t)(uint32_t)(k + 128) & 0xFFULL) << (8*i);
    }
    keyv[r] = key;
    h0[r] = (uint32_t)hmix(key) & TMASK;
    pbary[n*6+r] = (r==0) ? w0 : bar[r];
  }
  unsigned long long pk[6];
  #pragma unroll
  for (int r=0;r<6;r++) pk[r] = hs[h0[r]];           // 6 loads in flight
  // --- phase 2: resolve each vertex (stale peek is safe: CAS re-checks) ---
  #pragma unroll
  for (int r=0;r<6;r++){
    uint64_t key = keyv[r];
    uint64_t ins = key | ((uint64_t)(uint32_t)n << 41);   // owner embedded
    uint32_t h = h0[r];
    unsigned long long seen = pk[r];
    for (;;){
      if (seen != EMPTYK && (seen & KEYMASK) == (unsigned long long)key) break;
      if (seen == EMPTYK){
        unsigned long long prev = atomicCAS(&hs[h], EMPTYK, (unsigned long long)ins);
        if (prev == EMPTYK){
          atomicAdd(&s_hist[t >> 2], 1);   // LDS — block owns buckets (n>>2)
          break;
        }
        if ((prev & KEYMASK) == (unsigned long long)key) break;
      }
      h = (h + 1) & TMASK;
      seen = hs[h];
    }
    hslot[n*6+r] = (int)h;
  }
  __syncthreads();
  if (t < 64) hist[blockIdx.x*64 + t] = s_hist[t];   // plain coalesced store
}

// K2b: single-block scan of NBUCK bucket counts (32 serial buckets per thread)
__global__ __launch_bounds__(1024) void k_scan_small(const int* __restrict__ hist,
      int* __restrict__ bcur, int* __restrict__ counter){
  __shared__ int s[1024];
  int t = threadIdx.x;
  int base = t * (NBUCK/1024);
  int loc[NBUCK/1024];
  int sum = 0;
  #pragma unroll
  for (int i=0;i<NBUCK/1024;i++){ loc[i] = hist[base+i]; sum += loc[i]; }
  s[t] = sum;
  __syncthreads();
  #pragma unroll
  for (int o=1;o<1024;o<<=1){
    int add = (t>=o) ? s[t-o] : 0;
    __syncthreads();
    s[t] += add;
    __syncthreads();
  }
  int run = s[t] - sum;   // exclusive prefix for this thread's range
  #pragma unroll
  for (int i=0;i<NBUCK/1024;i++){ bcur[base+i] = run; run += loc[i]; }
  if (t == 1023) counter[0] = run;
}

// K2c: place occupied slots -> owner-bucket-ordered compact idx.
__global__ __launch_bounds__(1024) void k_place(unsigned long long* __restrict__ hs,
      int* __restrict__ bcur,
      unsigned long long* __restrict__ latkeys){
  uint32_t s = blockIdx.x*1024 + threadIdx.x;
  unsigned long long e = hs[s];
  if (e == EMPTYK) return;
  int nown = (int)(e >> 41);
  int idx = atomicAdd(&bcur[nown >> 2], 1);
  unsigned long long key = e & KEYMASK;
  hs[s] = key | ((unsigned long long)idx << 41);
  latkeys[idx] = key;
}

// K2d: precompute blur neighbor indices. Symmetry: +probe only, scatter the
// -neighbor. nbrx coalesced plane; nbry scattered 4B stores (memset to 0).
__global__ __launch_bounds__(256) void k_nbr(const unsigned long long* __restrict__ hs,
      const unsigned long long* __restrict__ latkeys, const int* __restrict__ counter,
      uint32_t* __restrict__ nbrx, uint32_t* __restrict__ nbry){
  int m = blockIdx.x*256 + threadIdx.x;
  if (m >= *counter) return;
  uint64_t key = (uint64_t)latkeys[m];
  const unsigned long long S5 = (1ULL<<32)+(1ULL<<24)+(1ULL<<16)+(1ULL<<8)+1ULL;
  #pragma unroll
  for (int j=0;j<6;j++){
    unsigned long long delta = (j<5) ? (S5 - (6ULL << (8*j))) : S5;
    int i1 = hlookup(hs, key + delta);
    nbrx[(size_t)j*NV + m] = (uint32_t)(i1+1);
    if (i1 >= 0) nbry[(size_t)j*NV + (uint32_t)i1] = (uint32_t)(m+1);
  }
}

// K3: pidx via recorded slot (ONE random 8B read) + segment-rank histogram.
// The atomicAdd return IS the pair's rank within its vertex segment — record
// it in hslot (read-then-overwrite, hslot dead afterwards). R20.
__global__ __launch_bounds__(256) void k_find(const unsigned long long* __restrict__ hs,
      int* __restrict__ hslot,
      int* __restrict__ pidx, int* __restrict__ cnt){
  int t = blockIdx.x*256 + threadIdx.x;
  if (t >= NV) return;
  int i = (int)(hs[hslot[t]] >> 41);
  pidx[t] = i;
  hslot[t] = atomicAdd(&cnt[i], 1);     // rank within segment
}

// Scan stage 1
__global__ __launch_bounds__(1024) void k_scan1(const int* __restrict__ cnt,
      int* __restrict__ off, int* __restrict__ bsum){
  __shared__ int s[1024];
  int t = threadIdx.x;
  int i = blockIdx.x*1024 + t;
  int v = cnt[i];
  s[t] = v;
  __syncthreads();
  #pragma unroll
  for (int o=1;o<1024;o<<=1){
    int add = (t>=o) ? s[t-o] : 0;
    __syncthreads();
    s[t] += add;
    __syncthreads();
  }
  off[i] = s[t] - v;
  if (t==1023) bsum[blockIdx.x] = s[t];
}

// Scan stage 2
__global__ __launch_bounds__(1024) void k_scan2(int* __restrict__ bsum){
  __shared__ int s[1024];
  int t = threadIdx.x;
  int v = (t < NBLK) ? bsum[t] : 0;
  s[t] = v;
  __syncthreads();
  #pragma unroll
  for (int o=1;o<1024;o<<=1){
    int add = (t>=o) ? s[t-o] : 0;
    __syncthreads();
    s[t] += add;
    __syncthreads();
  }
  if (t < NBLK) bsum[t] = s[t] - v;
}

// Scan stage 3: finalize off (exclusive segment START; never mutated again)
__global__ __launch_bounds__(1024) void k_scan3(int* __restrict__ off,
      const int* __restrict__ bsum){
  int i = blockIdx.x*1024 + threadIdx.x;
  off[i] += bsum[blockIdx.x];
}

// K4a: ATOMIC-FREE scatter — pos = off[vertex] + rank (recorded by k_find).
__global__ __launch_bounds__(256) void k_scatter(const int* __restrict__ pidx,
      const int* __restrict__ prank,
      const float* __restrict__ pbary, const int* __restrict__ off,
      uint2* __restrict__ plist2){
  int t = blockIdx.x*256 + threadIdx.x;
  if (t >= NV) return;
  int pos = off[pidx[t]] + prank[t];
  plist2[pos] = make_uint2((uint32_t)(t/6), __float_as_uint(pbary[t]));
}

// K4b: gather-reduce splat — fp16 xt rows (1 line/gather), fp32 acc, fp16 store
__global__ __launch_bounds__(256) void k_splat2(const __half* __restrict__ xt,
      const int* __restrict__ off, const int* __restrict__ cnt,
      const uint2* __restrict__ plist2, const int* __restrict__ counter,
      __half* __restrict__ lat){
  int m = blockIdx.x*256 + threadIdx.x;
  if (m >= *counter) return;
  float2 acc[12];
  #pragma unroll
  for (int q=0;q<12;q++) acc[q] = make_float2(0.f,0.f);
  int e0 = off[m], k = cnt[m];             // off[m] is the segment START
  for (int e=e0; e<e0+k; ++e){
    uint2 pv = plist2[e];
    float w = __uint_as_float(pv.y);
    float2 xr[12];
    row_load(xt + (size_t)pv.x*HCP, xr);
    #pragma unroll
    for (int q=0;q<12;q++){
      acc[q].x = fmaf(w, xr[q].x, acc[q].x);
      acc[q].y = fmaf(w, xr[q].y, acc[q].y);
    }
  }
  row_store(lat + (size_t)m*HCP, acc);
}

// K5: one blur direction via precomputed neighbor planes; fp32 math, fp16 rows
__global__ __launch_bounds__(256) void k_blur(const uint32_t* __restrict__ nx,
      const uint32_t* __restrict__ ny,
      const int* __restrict__ counter, const __half* __restrict__ src,
      __half* __restrict__ dst){
  int m = blockIdx.x*256 + threadIdx.x;
  if (m >= *counter) return;
  uint32_t ex = nx[m], ey = ny[m];
  float2 a[12], u[12], v[12];
  #pragma unroll
  for (int q=0;q<12;q++){ u[q] = make_float2(0.f,0.f); v[q] = make_float2(0.f,0.f); }
  row_load(src + (size_t)m*HCP, a);
  if (ex) row_load(src + (size_t)(ex-1u)*HCP, u);
  if (ey) row_load(src + (size_t)(ey-1u)*HCP, v);
  float2 r[12];
  #pragma unroll
  for (int q=0;q<12;q++){
    r[q].x = a[q].x + 0.5f*(u[q].x + v[q].x);
    r[q].y = a[q].y + 0.5f*(u[q].y + v[q].y);
  }
  row_store(dst + (size_t)m*HCP, r);
}

// K6: slice — out[b,c,y,x] = alpha * sum_r bary[r] * lat[idx[r]][c]
__global__ __launch_bounds__(256) void k_slice(const __half* __restrict__ lat,
      const int* __restrict__ pidx, const float* __restrict__ pbary,
      float* __restrict__ out){
  int n = blockIdx.x*256 + threadIdx.x;
  if (n >= NPT) return;
  float2 acc[12];
  #pragma unroll
  for (int q=0;q<12;q++) acc[q] = make_float2(0.f,0.f);
  #pragma unroll
  for (int r=0;r<6;r++){
    int idx = pidx[n*6+r]; float w = pbary[n*6+r];
    float2 L[12];
    row_load(lat + (size_t)idx*HCP, L);
    #pragma unroll
    for (int q=0;q<12;q++){
      acc[q].x = fmaf(w, L[q].x, acc[q].x);
      acc[q].y = fmaf(w, L[q].y, acc[q].y);
    }
  }
  int b = n >> 16, pix = n & 65535;
  float* ob = out + (((size_t)b*CC) << 16) + pix;
  const float alpha = 0.9696969696969697f;  // 1/(1+2^-5) = 32/33
  #pragma unroll
  for (int c=0;c<CC;c++){
    float val = (c & 1) ? acc[c>>1].y : acc[c>>1].x;
    ob[(size_t)c << 16] = alpha * val;
  }
}

extern "C" void kernel_launch(void* const* d_in, const int* in_sizes, int n_in,
                              void* d_out, int out_size, void* d_ws, size_t ws_size,
                              hipStream_t stream){
  const float* xin = (const float*)d_in[0];   // (2,21,256,256)
  const float* img = (const float*)d_in[1];   // (2,3,256,256)
  float* out = (float*)d_out;                 // (2,21,256,256)

  // workspace carve (each region 256B-aligned); cnt+nbry ADJACENT (one memset)
  char* p = (char*)d_ws;
  auto carve = [&](size_t bytes)->char*{
    char* r = p; p += (bytes + 255) & ~(size_t)255; return r;
  };
  unsigned long long* hs      = (unsigned long long*)carve((size_t)TS*8);   //  8.4 MB
  unsigned long long* latkeys = (unsigned long long*)carve((size_t)NV*8);   //  6.3 MB
  int*                counter = (int*)               carve(256);
  uint2*              plist2  = (uint2*)             carve((size_t)NV*8);   //  6.3 MB
  int*                pidx    = (int*)               carve((size_t)NV*4);   //  3.1 MB
  float*              pbary   = (float*)             carve((size_t)NV*4);   //  3.1 MB
  int*                hslot   = (int*)               carve((size_t)NV*4);   //  3.1 MB (-> prank after k_find)
  int*                cnt     = (int*)               carve((size_t)NV*4);   //  3.1 MB  (zeroed ↓)
  uint32_t*           nbry    = (uint32_t*)          carve((size_t)6*NV*4); // 18.9 MB  (zeroed ↓, adjacent to cnt)
  int*                off     = (int*)               carve((size_t)NV*4);   //  3.1 MB
  int*                bsum    = (int*)               carve((size_t)NBLK*4); //  3 KB
  int*                hist    = (int*)               carve((size_t)NBUCK*4);// 128 KB (fully written by k_build)
  int*                bcur    = (int*)               carve((size_t)NBUCK*4);// 128 KB
  uint32_t*           nbrx    = (uint32_t*)          carve((size_t)6*NV*4); // 18.9 MB
  __half*             latA    = (__half*)            carve((size_t)NV*HCP*2);// 50.3 MB
  __half*             latB    = (__half*)            carve((size_t)NV*HCP*2);// 50.3 MB

  // aliases (non-overlapping liveness):
  //   xt (fp16, NPT*64B = 8.4 MB) lives in latB — written by k_build, read
  //   only by k_splat2; blur j=0 overwrites latB strictly after splat.
  __half* xt = latB;

  (void)hipMemsetAsync(hs, 0xFF, (size_t)TS*8, stream);
  (void)hipMemsetAsync(cnt, 0, (size_t)(NV*4 + (size_t)6*NV*4), stream); // cnt+nbry

  k_build     <<<NPT/256, 256, 0, stream>>>(xin, img, hs, hist, pbary, hslot, xt);
  k_scan_small<<<1,      1024, 0, stream>>>(hist, bcur, counter);
  k_place     <<<TS/1024,1024, 0, stream>>>(hs, bcur, latkeys);
  k_nbr       <<<NV/256,  256, 0, stream>>>(hs, latkeys, counter, nbrx, nbry);
  k_find      <<<NV/256,  256, 0, stream>>>(hs, hslot, pidx, cnt);
  k_scan1     <<<NBLK,   1024, 0, stream>>>(cnt, off, bsum);
  k_scan2     <<<1,      1024, 0, stream>>>(bsum);
  k_scan3     <<<NBLK,   1024, 0, stream>>>(off, bsum);
  k_scatter   <<<NV/256,  256, 0, stream>>>(pidx, hslot, pbary, off, plist2);
  k_splat2    <<<NV/256,  256, 0, stream>>>(xt, off, cnt, plist2, counter, latA);

  // 6 blur passes, ping-pong latA <-> latB, using precomputed neighbor planes
  __half* src = latA; __half* dst = latB;
  for (int j=0;j<6;j++){
    k_blur<<<NV/256, 256, 0, stream>>>(nbrx + (size_t)j*NV, nbry + (size_t)j*NV,
                                       counter, src, dst);
    __half* tmp = src; src = dst; dst = tmp;
  }
  // after 6 swaps src == latA (final)
  k_slice<<<NPT/256, 256, 0, stream>>>(src, pidx, pbary, out);
}

// Round 10
// 332.442 us; speedup vs baseline: 1.1109x; 1.0284x over previous
//
#include <hip/hip_runtime.h>
#include <hip/hip_fp16.h>
#include <stdint.h>

// Problem constants (x: (2,21,256,256) f32, image: (2,3,256,256) f32, bilateral d=5)
#define BB   2
#define CC   21
#define HCP  32              // halves per lattice row (64 B = exactly 1 cache line)
#define NPT  (BB*256*256)    // 131072 points
#define DP1  6
#define NV   (NPT*DP1)       // 786432 point-vertex pairs (max unique keys)
#define TS   (1u<<20)        // hash slots (load ~52% — R14: halved for L2 hit rate)
#define TMASK (TS-1)
#define EMPTYK 0xFFFFFFFFFFFFFFFFULL
#define NBLK (NV/1024)       // 768 scan blocks (pair-count scan)
#define NBUCK 32768          // owner-pixel buckets (pixel id >> 2): dense & uniform
// 41-bit key: 5 coords x 8 bits (coord+128, each byte in [26,230]) + batch bit 40.
// bits 41..63 of the hash word: owner pixel id (build) then compact idx (place).
#define KEYMASK ((1ULL<<41)-1ULL)

// R7: do NOT swizzle blockIdx. R9: buckets must be load-uniform.
// R11/R12: fp16 64B lattice rows -> 1 line per random gather (611 -> 381 us).
// R13 (REVISED R21): insert is random-RMW-throughput-bound at >=8 waves/CU;
//      BELOW that, throughput scales with waves (half-grid 1.1 vs full 2.15
//      TB/s — r8/r9 counters). Never shrink the grid.
// R15: LDS histogram + dead-pkeys drop: WIN. Symmetric k_nbr: WIN.
// R16: CAS-first probing REGRESSED; peek-then-CAS + 6-way batched peeks: WIN.
// R19: cooperative launch ABANDONED (r5 silent reject, r6 hang under capture).
// R20: k_find records its atomicAdd return (segment rank) -> k_scatter
//      atomic-free: 45.7us -> <~12us. WIN.
// R21: k_build re-merged full-grid: 2x43us -> 53.5us total. WIN.
// R22 (this round): k_nbr and k_find are independent consumers of the placed
//      hash table, both random-access-bound, neither saturating. Fuse into one
//      NV-thread kernel (find for all t; nbr for t<counter) — the interleaved
//      request streams hide each other's latency; one less launch.

__device__ __forceinline__ uint64_t hmix(uint64_t x){
  x ^= x >> 33; x *= 0xff51afd7ed558ccdULL;
  x ^= x >> 33; x *= 0xc4ceb9fe1a85ec53ULL;
  x ^= x >> 33; return x;
}

__device__ __forceinline__ int hlookup(const unsigned long long* __restrict__ hs,
                                       uint64_t key){
  uint32_t h = (uint32_t)hmix(key) & TMASK;
  for (;;){
    unsigned long long e = hs[h];
    if (e == EMPTYK) return -1;
    if ((e & KEYMASK) == (unsigned long long)key) return (int)(e >> 41);
    h = (h + 1) & TMASK;
  }
}

// load first 24 halves (3x16B) of a 64B-aligned row -> 12 float2
__device__ __forceinline__ void row_load(const __half* p, float2 f[12]){
  const uint4* p4 = (const uint4*)p;
  #pragma unroll
  for (int i=0;i<3;i++){
    uint4 r = p4[i];
    const __half2* h = (const __half2*)&r;
    #pragma unroll
    for (int j=0;j<4;j++) f[i*4+j] = __half22float2(h[j]);
  }
}
// store 12 float2 -> first 24 halves of a row
__device__ __forceinline__ void row_store(__half* p, const float2 f[12]){
  uint4* p4 = (uint4*)p;
  #pragma unroll
  for (int i=0;i<3;i++){
    uint4 r;
    __half2* h = (__half2*)&r;
    #pragma unroll
    for (int j=0;j<4;j++) h[j] = __floats2half2_rn(f[i*4+j].x, f[i*4+j].y);
    p4[i] = r;
  }
}

// K1: fused transpose + per-point lattice math + hash insert (peek-then-CAS;
// 6 initial peeks as independent loads) + hslot recording. Bucket counts
// aggregate in LDS (bucket n>>2 is block-exclusive). Single full-grid launch.
__global__ __launch_bounds__(256) void k_build(const float* __restrict__ xin,
      const float* __restrict__ img,
      unsigned long long* __restrict__ hs,
      int* __restrict__ hist,
      float* __restrict__ pbary,
      int* __restrict__ hslot,
      __half* __restrict__ xt){
  __shared__ int s_hist[64];
  int t = threadIdx.x;
  if (t < 64) s_hist[t] = 0;
  __syncthreads();
  int n = blockIdx.x*256 + t;          // grid is exact: NPT/256 blocks
  int b = n >> 16, pix = n & 65535;
  int y = pix >> 8, x = pix & 255;
  // ---- fused k_tx: issue the 21 strided x loads early; they drain under the
  // lattice math and the store lands before the hash phase's random traffic ----
  const float* xb = xin + (((size_t)b*CC) << 16) + pix;
  float v12[12*2];
  #pragma unroll
  for (int q=0;q<12;q++){
    int c0 = 2*q, c1 = 2*q+1;
    v12[2*q]   = (c0 < CC) ? xb[(size_t)c0 << 16] : 0.f;
    v12[2*q+1] = (c1 < CC) ? xb[(size_t)c1 << 16] : 0.f;
  }
  // scale[j] = sqrt(2/3)*6 / sqrt((j+1)(j+2)), as float32 (numpy f64 -> f32)
  const float sc0 = 3.4641016151377544f, sc1 = 2.0f, sc2 = 1.4142135623730951f,
              sc3 = 1.0954451150103321f, sc4 = 0.8944271909999159f;
  size_t ib = ((size_t)b*3) << 16;
  float f0 = ((float)x / 80.0f) * sc0;                      // xs / THETA_ALPHA
  float f1 = ((float)y / 80.0f) * sc1;                      // ys / THETA_ALPHA
  float f2 = (img[ib + pix]          / 13.0f) * sc2;        // R / THETA_BETA
  float f3 = (img[ib + 65536 + pix]  / 13.0f) * sc3;        // G
  float f4 = (img[ib + 131072 + pix] / 13.0f) * sc4;        // B
  // elevate: E rows [1,1,1,1,1],[-1,1,1,1,1],[0,-2,1,1,1],[0,0,-3,1,1],[0,0,0,-4,1],[0,0,0,0,-5]
  float E[6];
  {
    float s4 = f4;
    E[5] = -5.0f*f4;
    E[4] = -4.0f*f3 + s4;
    float s3 = f3 + s4;
    E[3] = -3.0f*f2 + s3;
    float s2 = f2 + s3;
    E[2] = -2.0f*f1 + s2;
    float s1 = f1 + s2;
    E[1] = -f0 + s1;
    E[0] =  f0 + s1;
  }
  float rem0[6], di[6]; int rk[6];
  float ssf = 0.f;
  #pragma unroll
  for (int i=0;i<6;i++){
    float v  = E[i] / 6.0f;
    float up = ceilf(v)*6.0f, dn = floorf(v)*6.0f;
    float r0 = (up - E[i] < E[i] - dn) ? up : dn;
    rem0[i] = r0; di[i] = E[i] - r0; ssf += r0;     // di from PRE-wrap rem0
  }
  int ssum = (int)rintf(ssf / 6.0f);                 // exact: rem0 are multiples of 6
  #pragma unroll
  for (int i=0;i<6;i++){
    int c = ssum;
    #pragma unroll
    for (int k=0;k<6;k++){
      if (k==i) continue;
      bool tt = (k>i) ? (di[i] < di[k]) : (di[i] <= di[k]);
      c += tt ? 1 : 0;
    }
    rk[i] = c;
  }
  #pragma unroll
  for (int i=0;i<6;i++){
    if      (rk[i] < 0){ rk[i] += 6; rem0[i] += 6.0f; }
    else if (rk[i] > 5){ rk[i] -= 6; rem0[i] -= 6.0f; }
  }
  // barycentric: bar[5-rk] += t; bar[6-rk] -= t  (unrolled to keep in registers)
  float bar[7] = {0,0,0,0,0,0,0};
  #pragma unroll
  for (int i=0;i<6;i++){
    float tb = (E[i] - rem0[i]) / 6.0f;              // t from POST-wrap rem0
    #pragma unroll
    for (int j=0;j<7;j++){
      bar[j] += ((5-rk[i])==j) ? tb : 0.0f;
      bar[j] -= ((6-rk[i])==j) ? tb : 0.0f;
    }
  }
  float w0 = bar[0] + 1.0f + bar[6];
  int ri[5];
  #pragma unroll
  for (int i=0;i<5;i++) ri[i] = (int)rintf(rem0[i]);
  // store the transposed x row now (loads have drained under the math above)
  row_store(xt + (size_t)n*HCP, (const float2*)v12);
  uint64_t bbit = ((uint64_t)b) << 40;
  // --- phase 1: all 6 keys + initial hash slots; issue 6 independent peeks ---
  uint64_t keyv[6]; uint32_t h0[6];
  #pragma unroll
  for (int r=0;r<6;r++){
    uint64_t key = bbit;
    #pragma unroll
    for (int i=0;i<5;i++){
      int k = ri[i] + r - ((rk[i] > 5-r) ? 6 : 0);   // |k| <= 102 -> +128 in [26,230]
      key |= ((uint64_t)(uint32_t)(k + 128) & 0xFFULL) << (8*i);
    }
    keyv[r] = key;
    h0[r] = (uint32_t)hmix(key) & TMASK;
    pbary[n*6+r] = (r==0) ? w0 : bar[r];
  }
  unsigned long long pk[6];
  #pragma unroll
  for (int r=0;r<6;r++) pk[r] = hs[h0[r]];           // 6 loads in flight
  // --- phase 2: resolve each vertex (stale peek is safe: CAS re-checks) ---
  #pragma unroll
  for (int r=0;r<6;r++){
    uint64_t key = keyv[r];
    uint64_t ins = key | ((uint64_t)(uint32_t)n << 41);   // owner embedded
    uint32_t h = h0[r];
    unsigned long long seen = pk[r];
    for (;;){
      if (seen != EMPTYK && (seen & KEYMASK) == (unsigned long long)key) break;
      if (seen == EMPTYK){
        unsigned long long prev = atomicCAS(&hs[h], EMPTYK, (unsigned long long)ins);
        if (prev == EMPTYK){
          atomicAdd(&s_hist[t >> 2], 1);   // LDS — block owns buckets (n>>2)
          break;
        }
        if ((prev & KEYMASK) == (unsigned long long)key) break;
      }
      h = (h + 1) & TMASK;
      seen = hs[h];
    }
    hslot[n*6+r] = (int)h;
  }
  __syncthreads();
  if (t < 64) hist[blockIdx.x*64 + t] = s_hist[t];   // plain coalesced store
}

// K2b: single-block scan of NBUCK bucket counts (32 serial buckets per thread)
__global__ __launch_bounds__(1024) void k_scan_small(const int* __restrict__ hist,
      int* __restrict__ bcur, int* __restrict__ counter){
  __shared__ int s[1024];
  int t = threadIdx.x;
  int base = t * (NBUCK/1024);
  int loc[NBUCK/1024];
  int sum = 0;
  #pragma unroll
  for (int i=0;i<NBUCK/1024;i++){ loc[i] = hist[base+i]; sum += loc[i]; }
  s[t] = sum;
  __syncthreads();
  #pragma unroll
  for (int o=1;o<1024;o<<=1){
    int add = (t>=o) ? s[t-o] : 0;
    __syncthreads();
    s[t] += add;
    __syncthreads();
  }
  int run = s[t] - sum;   // exclusive prefix for this thread's range
  #pragma unroll
  for (int i=0;i<NBUCK/1024;i++){ bcur[base+i] = run; run += loc[i]; }
  if (t == 1023) counter[0] = run;
}

// K2c: place occupied slots -> owner-bucket-ordered compact idx.
__global__ __launch_bounds__(1024) void k_place(unsigned long long* __restrict__ hs,
      int* __restrict__ bcur,
      unsigned long long* __restrict__ latkeys){
  uint32_t s = blockIdx.x*1024 + threadIdx.x;
  unsigned long long e = hs[s];
  if (e == EMPTYK) return;
  int nown = (int)(e >> 41);
  int idx = atomicAdd(&bcur[nown >> 2], 1);
  unsigned long long key = e & KEYMASK;
  hs[s] = key | ((unsigned long long)idx << 41);
  latkeys[idx] = key;
}

// K2d+K3 fused (R22): find for every pair t, neighbor probes for vertex t.
// Both random-access-bound on the L2/L3-resident table; interleaving the
// streams raises outstanding-request count per wave.
__global__ __launch_bounds__(256) void k_nbr_find(
      const unsigned long long* __restrict__ hs,
      const unsigned long long* __restrict__ latkeys,
      const int* __restrict__ counter,
      uint32_t* __restrict__ nbrx, uint32_t* __restrict__ nbry,
      int* __restrict__ hslot, int* __restrict__ pidx, int* __restrict__ cnt){
  int t = blockIdx.x*256 + threadIdx.x;
  if (t >= NV) return;
  // --- find part (all t): pidx via recorded slot; record segment rank ---
  int i = (int)(hs[hslot[t]] >> 41);
  pidx[t] = i;
  hslot[t] = atomicAdd(&cnt[i], 1);     // rank within segment (R20)
  // --- nbr part (t < counter): +probe only, scatter the symmetric -nbr ---
  int m = t;
  if (m < *counter){
    uint64_t key = (uint64_t)latkeys[m];
    const unsigned long long S5 = (1ULL<<32)+(1ULL<<24)+(1ULL<<16)+(1ULL<<8)+1ULL;
    #pragma unroll
    for (int j=0;j<6;j++){
      unsigned long long delta = (j<5) ? (S5 - (6ULL << (8*j))) : S5;
      int i1 = hlookup(hs, key + delta);
      nbrx[(size_t)j*NV + m] = (uint32_t)(i1+1);
      if (i1 >= 0) nbry[(size_t)j*NV + (uint32_t)i1] = (uint32_t)(m+1);
    }
  }
}

// Scan stage 1
__global__ __launch_bounds__(1024) void k_scan1(const int* __restrict__ cnt,
      int* __restrict__ off, int* __restrict__ bsum){
  __shared__ int s[1024];
  int t = threadIdx.x;
  int i = blockIdx.x*1024 + t;
  int v = cnt[i];
  s[t] = v;
  __syncthreads();
  #pragma unroll
  for (int o=1;o<1024;o<<=1){
    int add = (t>=o) ? s[t-o] : 0;
    __syncthreads();
    s[t] += add;
    __syncthreads();
  }
  off[i] = s[t] - v;
  if (t==1023) bsum[blockIdx.x] = s[t];
}

// Scan stage 2
__global__ __launch_bounds__(1024) void k_scan2(int* __restrict__ bsum){
  __shared__ int s[1024];
  int t = threadIdx.x;
  int v = (t < NBLK) ? bsum[t] : 0;
  s[t] = v;
  __syncthreads();
  #pragma unroll
  for (int o=1;o<1024;o<<=1){
    int add = (t>=o) ? s[t-o] : 0;
    __syncthreads();
    s[t] += add;
    __syncthreads();
  }
  if (t < NBLK) bsum[t] = s[t] - v;
}

// Scan stage 3: finalize off (exclusive segment START; never mutated again)
__global__ __launch_bounds__(1024) void k_scan3(int* __restrict__ off,
      const int* __restrict__ bsum){
  int i = blockIdx.x*1024 + threadIdx.x;
  off[i] += bsum[blockIdx.x];
}

// K4a: ATOMIC-FREE scatter — pos = off[vertex] + rank (recorded by find).
__global__ __launch_bounds__(256) void k_scatter(const int* __restrict__ pidx,
      const int* __restrict__ prank,
      const float* __restrict__ pbary, const int* __restrict__ off,
      uint2* __restrict__ plist2){
  int t = blockIdx.x*256 + threadIdx.x;
  if (t >= NV) return;
  int pos = off[pidx[t]] + prank[t];
  plist2[pos] = make_uint2((uint32_t)(t/6), __float_as_uint(pbary[t]));
}

// K4b: gather-reduce splat — fp16 xt rows (1 line/gather), fp32 acc, fp16 store
__global__ __launch_bounds__(256) void k_splat2(const __half* __restrict__ xt,
      const int* __restrict__ off, const int* __restrict__ cnt,
      const uint2* __restrict__ plist2, const int* __restrict__ counter,
      __half* __restrict__ lat){
  int m = blockIdx.x*256 + threadIdx.x;
  if (m >= *counter) return;
  float2 acc[12];
  #pragma unroll
  for (int q=0;q<12;q++) acc[q] = make_float2(0.f,0.f);
  int e0 = off[m], k = cnt[m];             // off[m] is the segment START
  for (int e=e0; e<e0+k; ++e){
    uint2 pv = plist2[e];
    float w = __uint_as_float(pv.y);
    float2 xr[12];
    row_load(xt + (size_t)pv.x*HCP, xr);
    #pragma unroll
    for (int q=0;q<12;q++){
      acc[q].x = fmaf(w, xr[q].x, acc[q].x);
      acc[q].y = fmaf(w, xr[q].y, acc[q].y);
    }
  }
  row_store(lat + (size_t)m*HCP, acc);
}

// K5: one blur direction via precomputed neighbor planes; fp32 math, fp16 rows
__global__ __launch_bounds__(256) void k_blur(const uint32_t* __restrict__ nx,
      const uint32_t* __restrict__ ny,
      const int* __restrict__ counter, const __half* __restrict__ src,
      __half* __restrict__ dst){
  int m = blockIdx.x*256 + threadIdx.x;
  if (m >= *counter) return;
  uint32_t ex = nx[m], ey = ny[m];
  float2 a[12], u[12], v[12];
  #pragma unroll
  for (int q=0;q<12;q++){ u[q] = make_float2(0.f,0.f); v[q] = make_float2(0.f,0.f); }
  row_load(src + (size_t)m*HCP, a);
  if (ex) row_load(src + (size_t)(ex-1u)*HCP, u);
  if (ey) row_load(src + (size_t)(ey-1u)*HCP, v);
  float2 r[12];
  #pragma unroll
  for (int q=0;q<12;q++){
    r[q].x = a[q].x + 0.5f*(u[q].x + v[q].x);
    r[q].y = a[q].y + 0.5f*(u[q].y + v[q].y);
  }
  row_store(dst + (size_t)m*HCP, r);
}

// K6: slice — out[b,c,y,x] = alpha * sum_r bary[r] * lat[idx[r]][c]
__global__ __launch_bounds__(256) void k_slice(const __half* __restrict__ lat,
      const int* __restrict__ pidx, const float* __restrict__ pbary,
      float* __restrict__ out){
  int n = blockIdx.x*256 + threadIdx.x;
  if (n >= NPT) return;
  float2 acc[12];
  #pragma unroll
  for (int q=0;q<12;q++) acc[q] = make_float2(0.f,0.f);
  #pragma unroll
  for (int r=0;r<6;r++){
    int idx = pidx[n*6+r]; float w = pbary[n*6+r];
    float2 L[12];
    row_load(lat + (size_t)idx*HCP, L);
    #pragma unroll
    for (int q=0;q<12;q++){
      acc[q].x = fmaf(w, L[q].x, acc[q].x);
      acc[q].y = fmaf(w, L[q].y, acc[q].y);
    }
  }
  int b = n >> 16, pix = n & 65535;
  float* ob = out + (((size_t)b*CC) << 16) + pix;
  const float alpha = 0.9696969696969697f;  // 1/(1+2^-5) = 32/33
  #pragma unroll
  for (int c=0;c<CC;c++){
    float val = (c & 1) ? acc[c>>1].y : acc[c>>1].x;
    ob[(size_t)c << 16] = alpha * val;
  }
}

extern "C" void kernel_launch(void* const* d_in, const int* in_sizes, int n_in,
                              void* d_out, int out_size, void* d_ws, size_t ws_size,
                              hipStream_t stream){
  const float* xin = (const float*)d_in[0];   // (2,21,256,256)
  const float* img = (const float*)d_in[1];   // (2,3,256,256)
  float* out = (float*)d_out;                 // (2,21,256,256)

  // workspace carve (each region 256B-aligned); cnt+nbry ADJACENT (one memset)
  char* p = (char*)d_ws;
  auto carve = [&](size_t bytes)->char*{
    char* r = p; p += (bytes + 255) & ~(size_t)255; return r;
  };
  unsigned long long* hs      = (unsigned long long*)carve((size_t)TS*8);   //  8.4 MB
  unsigned long long* latkeys = (unsigned long long*)carve((size_t)NV*8);   //  6.3 MB
  int*                counter = (int*)               carve(256);
  uint2*              plist2  = (uint2*)             carve((size_t)NV*8);   //  6.3 MB
  int*                pidx    = (int*)               carve((size_t)NV*4);   //  3.1 MB
  float*              pbary   = (float*)             carve((size_t)NV*4);   //  3.1 MB
  int*                hslot   = (int*)               carve((size_t)NV*4);   //  3.1 MB (-> prank after find)
  int*                cnt     = (int*)               carve((size_t)NV*4);   //  3.1 MB  (zeroed ↓)
  uint32_t*           nbry    = (uint32_t*)          carve((size_t)6*NV*4); // 18.9 MB  (zeroed ↓, adjacent to cnt)
  int*                off     = (int*)               carve((size_t)NV*4);   //  3.1 MB
  int*                bsum    = (int*)               carve((size_t)NBLK*4); //  3 KB
  int*                hist    = (int*)               carve((size_t)NBUCK*4);// 128 KB (fully written by k_build)
  int*                bcur    = (int*)               carve((size_t)NBUCK*4);// 128 KB
  uint32_t*           nbrx    = (uint32_t*)          carve((size_t)6*NV*4); // 18.9 MB
  __half*             latA    = (__half*)            carve((size_t)NV*HCP*2);// 50.3 MB
  __half*             latB    = (__half*)            carve((size_t)NV*HCP*2);// 50.3 MB

  // aliases (non-overlapping liveness):
  //   xt (fp16, NPT*64B = 8.4 MB) lives in latB — written by k_build, read
  //   only by k_splat2; blur j=0 overwrites latB strictly after splat.
  __half* xt = latB;

  (void)hipMemsetAsync(hs, 0xFF, (size_t)TS*8, stream);
  (void)hipMemsetAsync(cnt, 0, (size_t)(NV*4 + (size_t)6*NV*4), stream); // cnt+nbry

  k_build     <<<NPT/256, 256, 0, stream>>>(xin, img, hs, hist, pbary, hslot, xt);
  k_scan_small<<<1,      1024, 0, stream>>>(hist, bcur, counter);
  k_place     <<<TS/1024,1024, 0, stream>>>(hs, bcur, latkeys);
  k_nbr_find  <<<NV/256,  256, 0, stream>>>(hs, latkeys, counter, nbrx, nbry,
                                            hslot, pidx, cnt);
  k_scan1     <<<NBLK,   1024, 0, stream>>>(cnt, off, bsum);
  k_scan2     <<<1,      1024, 0, stream>>>(bsum);
  k_scan3     <<<NBLK,   1024, 0, stream>>>(off, bsum);
  k_scatter   <<<NV/256,  256, 0, stream>>>(pidx, hslot, pbary, off, plist2);
  k_splat2    <<<NV/256,  256, 0, stream>>>(xt, off, cnt, plist2, counter, latA);

  // 6 blur passes, ping-pong latA <-> latB, using precomputed neighbor planes
  __half* src = latA; __half* dst = latB;
  for (int j=0;j<6;j++){
    k_blur<<<NV/256, 256, 0, stream>>>(nbrx + (size_t)j*NV, nbry + (size_t)j*NV,
                                       counter, src, dst);
    __half* tmp = src; src = dst; dst = tmp;
  }
  // after 6 swaps src == latA (final)
  k_slice<<<NPT/256, 256, 0, stream>>>(src, pidx, pbary, out);
}

// Round 11
// 322.774 us; speedup vs baseline: 1.1442x; 1.0300x over previous
//
#include <hip/hip_runtime.h>
#include <hip/hip_fp16.h>
#include <stdint.h>

// Problem constants (x: (2,21,256,256) f32, image: (2,3,256,256) f32, bilateral d=5)
#define BB   2
#define CC   21
#define HCP  32              // halves per lattice row (64 B = exactly 1 cache line)
#define NPT  (BB*256*256)    // 131072 points
#define DP1  6
#define NV   (NPT*DP1)       // 786432 point-vertex pairs (max unique keys)
#define TS   (1u<<20)        // hash slots (load ~52% — R14: halved for L2 hit rate)
#define TMASK (TS-1)
#define EMPTYK 0xFFFFFFFFFFFFFFFFULL
#define NBLK (NV/1024)       // 768 scan blocks (pair-count scan)
#define NBUCK 32768          // owner-pixel buckets (pixel id >> 2): dense & uniform
// 41-bit key: 5 coords x 8 bits (coord+128, each byte in [26,230]) + batch bit 40.
// bits 41..63 of the hash word: owner pixel id (build) then compact idx (place).
#define KEYMASK ((1ULL<<41)-1ULL)

// R7: do NOT swizzle blockIdx. R9: buckets must be load-uniform.
// R11/R12: fp16 64B lattice rows -> 1 line per random gather (611 -> 381 us).
// R13/R21: random-RMW throughput saturates at >=8 waves/CU; below that it
//      scales with waves. Never shrink the grid.
// R15: LDS histogram + dead-pkeys drop: WIN. Symmetric k_nbr: WIN.
// R16: CAS-first probing REGRESSED; peek-then-CAS + batched peeks: WIN.
// R19: cooperative launch ABANDONED (r5 silent reject, r6 hang under capture).
// R20: find records atomicAdd return (segment rank) -> scatter atomic-free. WIN.
// R21: k_build full-grid re-merge: WIN. R22: nbr+find fusion: +9us pipeline.
// R23 (this round): (a) k_nbr_find's 6 probe chains were control-flow
//      serialized — batch all 7 initial random reads (find + 6 chain heads)
//      for 7-way MLP, same trick as build's R16; (b) fold scan3 into
//      scatter/splat (they add bsum[i>>10] themselves, 3KB L2-resident) —
//      one less NV-wide pass. Pipeline model: ~14M random lines x 64B
//      ~ 900MB @ ~2.7TB/s ~ 330us — we are near the decomposition floor;
//      these are the last structural inefficiencies identified.

__device__ __forceinline__ uint64_t hmix(uint64_t x){
  x ^= x >> 33; x *= 0xff51afd7ed558ccdULL;
  x ^= x >> 33; x *= 0xc4ceb9fe1a85ec53ULL;
  x ^= x >> 33; return x;
}

// load first 24 halves (3x16B) of a 64B-aligned row -> 12 float2
__device__ __forceinline__ void row_load(const __half* p, float2 f[12]){
  const uint4* p4 = (const uint4*)p;
  #pragma unroll
  for (int i=0;i<3;i++){
    uint4 r = p4[i];
    const __half2* h = (const __half2*)&r;
    #pragma unroll
    for (int j=0;j<4;j++) f[i*4+j] = __half22float2(h[j]);
  }
}
// store 12 float2 -> first 24 halves of a row
__device__ __forceinline__ void row_store(__half* p, const float2 f[12]){
  uint4* p4 = (uint4*)p;
  #pragma unroll
  for (int i=0;i<3;i++){
    uint4 r;
    __half2* h = (__half2*)&r;
    #pragma unroll
    for (int j=0;j<4;j++) h[j] = __floats2half2_rn(f[i*4+j].x, f[i*4+j].y);
    p4[i] = r;
  }
}

// K1: fused transpose + per-point lattice math + hash insert (peek-then-CAS;
// 6 initial peeks as independent loads) + hslot recording. Bucket counts
// aggregate in LDS (bucket n>>2 is block-exclusive). Single full-grid launch.
__global__ __launch_bounds__(256) void k_build(const float* __restrict__ xin,
      const float* __restrict__ img,
      unsigned long long* __restrict__ hs,
      int* __restrict__ hist,
      float* __restrict__ pbary,
      int* __restrict__ hslot,
      __half* __restrict__ xt){
  __shared__ int s_hist[64];
  int t = threadIdx.x;
  if (t < 64) s_hist[t] = 0;
  __syncthreads();
  int n = blockIdx.x*256 + t;          // grid is exact: NPT/256 blocks
  int b = n >> 16, pix = n & 65535;
  int y = pix >> 8, x = pix & 255;
  // ---- fused k_tx: issue the 21 strided x loads early; they drain under the
  // lattice math and the store lands before the hash phase's random traffic ----
  const float* xb = xin + (((size_t)b*CC) << 16) + pix;
  float v12[12*2];
  #pragma unroll
  for (int q=0;q<12;q++){
    int c0 = 2*q, c1 = 2*q+1;
    v12[2*q]   = (c0 < CC) ? xb[(size_t)c0 << 16] : 0.f;
    v12[2*q+1] = (c1 < CC) ? xb[(size_t)c1 << 16] : 0.f;
  }
  // scale[j] = sqrt(2/3)*6 / sqrt((j+1)(j+2)), as float32 (numpy f64 -> f32)
  const float sc0 = 3.4641016151377544f, sc1 = 2.0f, sc2 = 1.4142135623730951f,
              sc3 = 1.0954451150103321f, sc4 = 0.8944271909999159f;
  size_t ib = ((size_t)b*3) << 16;
  float f0 = ((float)x / 80.0f) * sc0;                      // xs / THETA_ALPHA
  float f1 = ((float)y / 80.0f) * sc1;                      // ys / THETA_ALPHA
  float f2 = (img[ib + pix]          / 13.0f) * sc2;        // R / THETA_BETA
  float f3 = (img[ib + 65536 + pix]  / 13.0f) * sc3;        // G
  float f4 = (img[ib + 131072 + pix] / 13.0f) * sc4;        // B
  // elevate: E rows [1,1,1,1,1],[-1,1,1,1,1],[0,-2,1,1,1],[0,0,-3,1,1],[0,0,0,-4,1],[0,0,0,0,-5]
  float E[6];
  {
    float s4 = f4;
    E[5] = -5.0f*f4;
    E[4] = -4.0f*f3 + s4;
    float s3 = f3 + s4;
    E[3] = -3.0f*f2 + s3;
    float s2 = f2 + s3;
    E[2] = -2.0f*f1 + s2;
    float s1 = f1 + s2;
    E[1] = -f0 + s1;
    E[0] =  f0 + s1;
  }
  float rem0[6], di[6]; int rk[6];
  float ssf = 0.f;
  #pragma unroll
  for (int i=0;i<6;i++){
    float v  = E[i] / 6.0f;
    float up = ceilf(v)*6.0f, dn = floorf(v)*6.0f;
    float r0 = (up - E[i] < E[i] - dn) ? up : dn;
    rem0[i] = r0; di[i] = E[i] - r0; ssf += r0;     // di from PRE-wrap rem0
  }
  int ssum = (int)rintf(ssf / 6.0f);                 // exact: rem0 are multiples of 6
  #pragma unroll
  for (int i=0;i<6;i++){
    int c = ssum;
    #pragma unroll
    for (int k=0;k<6;k++){
      if (k==i) continue;
      bool tt = (k>i) ? (di[i] < di[k]) : (di[i] <= di[k]);
      c += tt ? 1 : 0;
    }
    rk[i] = c;
  }
  #pragma unroll
  for (int i=0;i<6;i++){
    if      (rk[i] < 0){ rk[i] += 6; rem0[i] += 6.0f; }
    else if (rk[i] > 5){ rk[i] -= 6; rem0[i] -= 6.0f; }
  }
  // barycentric: bar[5-rk] += t; bar[6-rk] -= t  (unrolled to keep in registers)
  float bar[7] = {0,0,0,0,0,0,0};
  #pragma unroll
  for (int i=0;i<6;i++){
    float tb = (E[i] - rem0[i]) / 6.0f;              // t from POST-wrap rem0
    #pragma unroll
    for (int j=0;j<7;j++){
      bar[j] += ((5-rk[i])==j) ? tb : 0.0f;
      bar[j] -= ((6-rk[i])==j) ? tb : 0.0f;
    }
  }
  float w0 = bar[0] + 1.0f + bar[6];
  int ri[5];
  #pragma unroll
  for (int i=0;i<5;i++) ri[i] = (int)rintf(rem0[i]);
  // store the transposed x row now (loads have drained under the math above)
  row_store(xt + (size_t)n*HCP, (const float2*)v12);
  uint64_t bbit = ((uint64_t)b) << 40;
  // --- phase 1: all 6 keys + initial hash slots; issue 6 independent peeks ---
  uint64_t keyv[6]; uint32_t h0[6];
  #pragma unroll
  for (int r=0;r<6;r++){
    uint64_t key = bbit;
    #pragma unroll
    for (int i=0;i<5;i++){
      int k = ri[i] + r - ((rk[i] > 5-r) ? 6 : 0);   // |k| <= 102 -> +128 in [26,230]
      key |= ((uint64_t)(uint32_t)(k + 128) & 0xFFULL) << (8*i);
    }
    keyv[r] = key;
    h0[r] = (uint32_t)hmix(key) & TMASK;
    pbary[n*6+r] = (r==0) ? w0 : bar[r];
  }
  unsigned long long pk[6];
  #pragma unroll
  for (int r=0;r<6;r++) pk[r] = hs[h0[r]];           // 6 loads in flight
  // --- phase 2: resolve each vertex (stale peek is safe: CAS re-checks) ---
  #pragma unroll
  for (int r=0;r<6;r++){
    uint64_t key = keyv[r];
    uint64_t ins = key | ((uint64_t)(uint32_t)n << 41);   // owner embedded
    uint32_t h = h0[r];
    unsigned long long seen = pk[r];
    for (;;){
      if (seen != EMPTYK && (seen & KEYMASK) == (unsigned long long)key) break;
      if (seen == EMPTYK){
        unsigned long long prev = atomicCAS(&hs[h], EMPTYK, (unsigned long long)ins);
        if (prev == EMPTYK){
          atomicAdd(&s_hist[t >> 2], 1);   // LDS — block owns buckets (n>>2)
          break;
        }
        if ((prev & KEYMASK) == (unsigned long long)key) break;
      }
      h = (h + 1) & TMASK;
      seen = hs[h];
    }
    hslot[n*6+r] = (int)h;
  }
  __syncthreads();
  if (t < 64) hist[blockIdx.x*64 + t] = s_hist[t];   // plain coalesced store
}

// K2b: single-block scan of NBUCK bucket counts (32 serial buckets per thread)
__global__ __launch_bounds__(1024) void k_scan_small(const int* __restrict__ hist,
      int* __restrict__ bcur, int* __restrict__ counter){
  __shared__ int s[1024];
  int t = threadIdx.x;
  int base = t * (NBUCK/1024);
  int loc[NBUCK/1024];
  int sum = 0;
  #pragma unroll
  for (int i=0;i<NBUCK/1024;i++){ loc[i] = hist[base+i]; sum += loc[i]; }
  s[t] = sum;
  __syncthreads();
  #pragma unroll
  for (int o=1;o<1024;o<<=1){
    int add = (t>=o) ? s[t-o] : 0;
    __syncthreads();
    s[t] += add;
    __syncthreads();
  }
  int run = s[t] - sum;   // exclusive prefix for this thread's range
  #pragma unroll
  for (int i=0;i<NBUCK/1024;i++){ bcur[base+i] = run; run += loc[i]; }
  if (t == 1023) counter[0] = run;
}

// K2c: place occupied slots -> owner-bucket-ordered compact idx.
__global__ __launch_bounds__(1024) void k_place(unsigned long long* __restrict__ hs,
      int* __restrict__ bcur,
      unsigned long long* __restrict__ latkeys){
  uint32_t s = blockIdx.x*1024 + threadIdx.x;
  unsigned long long e = hs[s];
  if (e == EMPTYK) return;
  int nown = (int)(e >> 41);
  int idx = atomicAdd(&bcur[nown >> 2], 1);
  unsigned long long key = e & KEYMASK;
  hs[s] = key | ((unsigned long long)idx << 41);
  latkeys[idx] = key;
}

// K2d+K3 fused, R23: ALL 7 initial random reads (1 find + 6 probe-chain
// heads) issued before any resolution — 7-way MLP per thread.
__global__ __launch_bounds__(256) void k_nbr_find(
      const unsigned long long* __restrict__ hs,
      const unsigned long long* __restrict__ latkeys,
      const int* __restrict__ counter,
      uint32_t* __restrict__ nbrx, uint32_t* __restrict__ nbry,
      int* __restrict__ hslot, int* __restrict__ pidx, int* __restrict__ cnt){
  int t = blockIdx.x*256 + threadIdx.x;
  if (t >= NV) return;
  const int c = *counter;
  const bool active = (t < c);
  // --- phase 1: compute all hashes, issue all initial loads ---
  int slot = hslot[t];
  uint64_t nkey[6]; uint32_t nh[6];
  if (active){
    uint64_t key = (uint64_t)latkeys[t];
    const unsigned long long S5 = (1ULL<<32)+(1ULL<<24)+(1ULL<<16)+(1ULL<<8)+1ULL;
    #pragma unroll
    for (int j=0;j<6;j++){
      unsigned long long delta = (j<5) ? (S5 - (6ULL << (8*j))) : S5;
      nkey[j] = key + delta;
      nh[j] = (uint32_t)hmix(nkey[j]) & TMASK;
    }
  }
  unsigned long long fe = hs[slot];                 // find read
  unsigned long long ne[6];
  if (active){
    #pragma unroll
    for (int j=0;j<6;j++) ne[j] = hs[nh[j]];        // 6 chain heads in flight
  }
  // --- phase 2: resolve find (pidx + segment rank via atomic return, R20) ---
  int i = (int)(fe >> 41);
  pidx[t] = i;
  hslot[t] = atomicAdd(&cnt[i], 1);
  // --- phase 3: resolve the 6 probe chains; scatter symmetric -neighbor ---
  if (active){
    #pragma unroll
    for (int j=0;j<6;j++){
      unsigned long long e = ne[j];
      uint32_t h = nh[j];
      int i1;
      for (;;){
        if (e == EMPTYK){ i1 = -1; break; }
        if ((e & KEYMASK) == (unsigned long long)nkey[j]){ i1 = (int)(e >> 41); break; }
        h = (h + 1) & TMASK;
        e = hs[h];
      }
      nbrx[(size_t)j*NV + t] = (uint32_t)(i1+1);
      if (i1 >= 0) nbry[(size_t)j*NV + (uint32_t)i1] = (uint32_t)(t+1);
    }
  }
}

// Scan stage 1
__global__ __launch_bounds__(1024) void k_scan1(const int* __restrict__ cnt,
      int* __restrict__ off, int* __restrict__ bsum){
  __shared__ int s[1024];
  int t = threadIdx.x;
  int i = blockIdx.x*1024 + t;
  int v = cnt[i];
  s[t] = v;
  __syncthreads();
  #pragma unroll
  for (int o=1;o<1024;o<<=1){
    int add = (t>=o) ? s[t-o] : 0;
    __syncthreads();
    s[t] += add;
    __syncthreads();
  }
  off[i] = s[t] - v;
  if (t==1023) bsum[blockIdx.x] = s[t];
}

// Scan stage 2
__global__ __launch_bounds__(1024) void k_scan2(int* __restrict__ bsum){
  __shared__ int s[1024];
  int t = threadIdx.x;
  int v = (t < NBLK) ? bsum[t] : 0;
  s[t] = v;
  __syncthreads();
  #pragma unroll
  for (int o=1;o<1024;o<<=1){
    int add = (t>=o) ? s[t-o] : 0;
    __syncthreads();
    s[t] += add;
    __syncthreads();
  }
  if (t < NBLK) bsum[t] = s[t] - v;
}

// (scan3 folded into scatter/splat: true_off(i) = off[i] + bsum[i>>10] — R23)

// K4a: ATOMIC-FREE scatter — pos = off[v]+bsum[v>>10] + rank (bsum 3KB, cached)
__global__ __launch_bounds__(256) void k_scatter(const int* __restrict__ pidx,
      const int* __restrict__ prank,
      const float* __restrict__ pbary, const int* __restrict__ off,
      const int* __restrict__ bsum,
      uint2* __restrict__ plist2){
  int t = blockIdx.x*256 + threadIdx.x;
  if (t >= NV) return;
  int idx = pidx[t];
  int pos = off[idx] + bsum[idx >> 10] + prank[t];
  plist2[pos] = make_uint2((uint32_t)(t/6), __float_as_uint(pbary[t]));
}

// K4b: gather-reduce splat — fp16 xt rows (1 line/gather), fp32 acc, fp16 store
__global__ __launch_bounds__(256) void k_splat2(const __half* __restrict__ xt,
      const int* __restrict__ off, const int* __restrict__ bsum,
      const int* __restrict__ cnt,
      const uint2* __restrict__ plist2, const int* __restrict__ counter,
      __half* __restrict__ lat){
  int m = blockIdx.x*256 + threadIdx.x;
  if (m >= *counter) return;
  float2 acc[12];
  #pragma unroll
  for (int q=0;q<12;q++) acc[q] = make_float2(0.f,0.f);
  int e0 = off[m] + bsum[m >> 10], k = cnt[m];   // segment START
  for (int e=e0; e<e0+k; ++e){
    uint2 pv = plist2[e];
    float w = __uint_as_float(pv.y);
    float2 xr[12];
    row_load(xt + (size_t)pv.x*HCP, xr);
    #pragma unroll
    for (int q=0;q<12;q++){
      acc[q].x = fmaf(w, xr[q].x, acc[q].x);
      acc[q].y = fmaf(w, xr[q].y, acc[q].y);
    }
  }
  row_store(lat + (size_t)m*HCP, acc);
}

// K5: one blur direction via precomputed neighbor planes; fp32 math, fp16 rows
__global__ __launch_bounds__(256) void k_blur(const uint32_t* __restrict__ nx,
      const uint32_t* __restrict__ ny,
      const int* __restrict__ counter, const __half* __restrict__ src,
      __half* __restrict__ dst){
  int m = blockIdx.x*256 + threadIdx.x;
  if (m >= *counter) return;
  uint32_t ex = nx[m], ey = ny[m];
  float2 a[12], u[12], v[12];
  #pragma unroll
  for (int q=0;q<12;q++){ u[q] = make_float2(0.f,0.f); v[q] = make_float2(0.f,0.f); }
  row_load(src + (size_t)m*HCP, a);
  if (ex) row_load(src + (size_t)(ex-1u)*HCP, u);
  if (ey) row_load(src + (size_t)(ey-1u)*HCP, v);
  float2 r[12];
  #pragma unroll
  for (int q=0;q<12;q++){
    r[q].x = a[q].x + 0.5f*(u[q].x + v[q].x);
    r[q].y = a[q].y + 0.5f*(u[q].y + v[q].y);
  }
  row_store(dst + (size_t)m*HCP, r);
}

// K6: slice — out[b,c,y,x] = alpha * sum_r bary[r] * lat[idx[r]][c]
__global__ __launch_bounds__(256) void k_slice(const __half* __restrict__ lat,
      const int* __restrict__ pidx, const float* __restrict__ pbary,
      float* __restrict__ out){
  int n = blockIdx.x*256 + threadIdx.x;
  if (n >= NPT) return;
  float2 acc[12];
  #pragma unroll
  for (int q=0;q<12;q++) acc[q] = make_float2(0.f,0.f);
  #pragma unroll
  for (int r=0;r<6;r++){
    int idx = pidx[n*6+r]; float w = pbary[n*6+r];
    float2 L[12];
    row_load(lat + (size_t)idx*HCP, L);
    #pragma unroll
    for (int q=0;q<12;q++){
      acc[q].x = fmaf(w, L[q].x, acc[q].x);
      acc[q].y = fmaf(w, L[q].y, acc[q].y);
    }
  }
  int b = n >> 16, pix = n & 65535;
  float* ob = out + (((size_t)b*CC) << 16) + pix;
  const float alpha = 0.9696969696969697f;  // 1/(1+2^-5) = 32/33
  #pragma unroll
  for (int c=0;c<CC;c++){
    float val = (c & 1) ? acc[c>>1].y : acc[c>>1].x;
    ob[(size_t)c << 16] = alpha * val;
  }
}

extern "C" void kernel_launch(void* const* d_in, const int* in_sizes, int n_in,
                              void* d_out, int out_size, void* d_ws, size_t ws_size,
                              hipStream_t stream){
  const float* xin = (const float*)d_in[0];   // (2,21,256,256)
  const float* img = (const float*)d_in[1];   // (2,3,256,256)
  float* out = (float*)d_out;                 // (2,21,256,256)

  // workspace carve (each region 256B-aligned); cnt+nbry ADJACENT (one memset)
  char* p = (char*)d_ws;
  auto carve = [&](size_t bytes)->char*{
    char* r = p; p += (bytes + 255) & ~(size_t)255; return r;
  };
  unsigned long long* hs      = (unsigned long long*)carve((size_t)TS*8);   //  8.4 MB
  unsigned long long* latkeys = (unsigned long long*)carve((size_t)NV*8);   //  6.3 MB
  int*                counter = (int*)               carve(256);
  uint2*              plist2  = (uint2*)             carve((size_t)NV*8);   //  6.3 MB
  int*                pidx    = (int*)               carve((size_t)NV*4);   //  3.1 MB
  float*              pbary   = (float*)             carve((size_t)NV*4);   //  3.1 MB
  int*                hslot   = (int*)               carve((size_t)NV*4);   //  3.1 MB (-> prank after find)
  int*                cnt     = (int*)               carve((size_t)NV*4);   //  3.1 MB  (zeroed ↓)
  uint32_t*           nbry    = (uint32_t*)          carve((size_t)6*NV*4); // 18.9 MB  (zeroed ↓, adjacent to cnt)
  int*                off     = (int*)               carve((size_t)NV*4);   //  3.1 MB
  int*                bsum    = (int*)               carve((size_t)NBLK*4); //  3 KB
  int*                hist    = (int*)               carve((size_t)NBUCK*4);// 128 KB (fully written by k_build)
  int*                bcur    = (int*)               carve((size_t)NBUCK*4);// 128 KB
  uint32_t*           nbrx    = (uint32_t*)          carve((size_t)6*NV*4); // 18.9 MB
  __half*             latA    = (__half*)            carve((size_t)NV*HCP*2);// 50.3 MB
  __half*             latB    = (__half*)            carve((size_t)NV*HCP*2);// 50.3 MB

  // aliases (non-overlapping liveness):
  //   xt (fp16, NPT*64B = 8.4 MB) lives in latB — written by k_build, read
  //   only by k_splat2; blur j=0 overwrites latB strictly after splat.
  __half* xt = latB;

  (void)hipMemsetAsync(hs, 0xFF, (size_t)TS*8, stream);
  (void)hipMemsetAsync(cnt, 0, (size_t)(NV*4 + (size_t)6*NV*4), stream); // cnt+nbry

  k_build     <<<NPT/256, 256, 0, stream>>>(xin, img, hs, hist, pbary, hslot, xt);
  k_scan_small<<<1,      1024, 0, stream>>>(hist, bcur, counter);
  k_place     <<<TS/1024,1024, 0, stream>>>(hs, bcur, latkeys);
  k_nbr_find  <<<NV/256,  256, 0, stream>>>(hs, latkeys, counter, nbrx, nbry,
                                            hslot, pidx, cnt);
  k_scan1     <<<NBLK,   1024, 0, stream>>>(cnt, off, bsum);
  k_scan2     <<<1,      1024, 0, stream>>>(bsum);
  k_scatter   <<<NV/256,  256, 0, stream>>>(pidx, hslot, pbary, off, bsum, plist2);
  k_splat2    <<<NV/256,  256, 0, stream>>>(xt, off, bsum, cnt, plist2, counter, latA);

  // 6 blur passes, ping-pong latA <-> latB, using precomputed neighbor planes
  __half* src = latA; __half* dst = latB;
  for (int j=0;j<6;j++){
    k_blur<<<NV/256, 256, 0, stream>>>(nbrx + (size_t)j*NV, nbry + (size_t)j*NV,
                                       counter, src, dst);
    __half* tmp = src; src = dst; dst = tmp;
  }
  // after 6 swaps src == latA (final)
  k_slice<<<NPT/256, 256, 0, stream>>>(src, pidx, pbary, out);
}